// Round 1
// baseline (488.179 us; speedup 1.0000x reference)
//
#include <hip/hip_runtime.h>

typedef __attribute__((ext_vector_type(8))) __bf16 bf16x8;
typedef __attribute__((ext_vector_type(8))) unsigned short u16x8;
typedef __attribute__((ext_vector_type(4))) unsigned short u16x4;
typedef __attribute__((ext_vector_type(4))) float f32x4;

__device__ __forceinline__ unsigned short f2bf(float f) {
  union { float f; unsigned int u; } v; v.f = f;
  unsigned int r = v.u + 0x7fffu + ((v.u >> 16) & 1u);
  return (unsigned short)(r >> 16);
}

__device__ __forceinline__ bf16x8 ldb8(const unsigned short* p) {
  u16x8 u = *(const u16x8*)p;
  return __builtin_bit_cast(bf16x8, u);
}

__device__ __forceinline__ f32x4 mfma16(bf16x8 a, bf16x8 b, f32x4 c) {
  return __builtin_amdgcn_mfma_f32_16x16x32_bf16(a, b, c, 0, 0, 0);
}

__device__ __forceinline__ void gload16(const void* g, void* l) {
  __builtin_amdgcn_global_load_lds(
      (const __attribute__((address_space(1))) void*)g,
      (__attribute__((address_space(3))) void*)l, 16, 0, 0);
}

__device__ __forceinline__ float gelu_t(float x) {
  float u = x * (0.7978845608028654f * (1.0f + 0.044715f * x * x));
  return 0.5f * x * (1.0f + u / (1.0f + fabsf(u)));
}

// ---------------- transpose + fp32->bf16 convert: out[C][R] = bf16(in[R][C]) --------------
__global__ __launch_bounds__(256) void tconv_kernel(const float* __restrict__ in,
                                                    unsigned short* __restrict__ out,
                                                    int R, int C) {
  __shared__ unsigned short tile[64][68];
  int r0 = blockIdx.y * 64, c0 = blockIdx.x * 64;
  int tx = threadIdx.x & 63, tg = threadIdx.x >> 6;
  for (int rr = tg; rr < 64; rr += 4)
    tile[tx][rr] = f2bf(in[(size_t)(r0 + rr) * C + c0 + tx]);
  __syncthreads();
  for (int cc = tg; cc < 64; cc += 4)
    out[(size_t)(c0 + cc) * R + r0 + tx] = tile[cc][tx];
}

// ---------------- LayerNorm: one block per row of 1024, bf16 out -------------------------
__global__ __launch_bounds__(256) void ln_kernel(const float* __restrict__ X,
                                                 const float* __restrict__ W,
                                                 const float* __restrict__ Bv,
                                                 unsigned short* __restrict__ H) {
  int row = blockIdx.x;
  int t = threadIdx.x;
  float4 v = ((const float4*)(X + (size_t)row * 1024))[t];
  float s = v.x + v.y + v.z + v.w;
  float s2 = v.x * v.x + v.y * v.y + v.z * v.z + v.w * v.w;
#pragma unroll
  for (int m = 32; m >= 1; m >>= 1) { s += __shfl_xor(s, m); s2 += __shfl_xor(s2, m); }
  __shared__ float red[8];
  if ((t & 63) == 0) { red[t >> 6] = s; red[4 + (t >> 6)] = s2; }
  __syncthreads();
  s = red[0] + red[1] + red[2] + red[3];
  s2 = red[4] + red[5] + red[6] + red[7];
  float mean = s * (1.f / 1024.f);
  float var = fmaxf(s2 * (1.f / 1024.f) - mean * mean, 0.f);
  float rs = rsqrtf(var + 1e-5f);
  float4 w4 = ((const float4*)W)[t];
  float4 b4 = ((const float4*)Bv)[t];
  u16x4 o;
  o[0] = f2bf((v.x - mean) * rs * w4.x + b4.x);
  o[1] = f2bf((v.y - mean) * rs * w4.y + b4.y);
  o[2] = f2bf((v.z - mean) * rs * w4.z + b4.z);
  o[3] = f2bf((v.w - mean) * rs * w4.w + b4.w);
  *(u16x4*)(H + (size_t)row * 1024 + t * 4) = o;
}

// ---------------- GEMM: C[M][N] = A[M][K] * B_T[N][K]^T, bf16 in, MFMA ------------------
// MODE 0: qkv epilogue (scatter Q,K to [B,H,T,64]; V transposed to [B,H,64,T])
// MODE 1: fp32 out = acc + RES
// MODE 2: bf16 out = gelu(acc)
template <int MODE>
__global__ __launch_bounds__(256) void gemm_kernel(
    const unsigned short* __restrict__ A, const unsigned short* __restrict__ B,
    const float* __restrict__ RES, void* __restrict__ OUT,
    unsigned short* __restrict__ Qo, unsigned short* __restrict__ Ko,
    unsigned short* __restrict__ VT, int M, int N, int K) {
  __shared__ __align__(16) unsigned short As[128 * 64];
  __shared__ __align__(16) unsigned short Bs[128 * 64];
  const int tid = threadIdx.x;
  const int lane = tid & 63;
  const int wid = __builtin_amdgcn_readfirstlane(tid >> 6);
  const int lane16 = lane & 15, lgrp = lane >> 4;
  const int l8 = lane >> 3;
  const int lb = (lane & 7) * 16;
  const int m0 = blockIdx.y * 128, n0 = blockIdx.x * 128;
  const int wr = wid >> 1, wc = wid & 1;

  f32x4 acc[4][4] = {};

  const char* Ab = (const char*)A + (size_t)m0 * K * 2;
  const char* Bb = (const char*)B + (size_t)n0 * K * 2;
  const size_t rs = (size_t)K * 2;

  for (int k0 = 0; k0 < K; k0 += 64) {
#pragma unroll
    for (int i = 0; i < 4; ++i) {
      int c = wid * 4 + i;
      gload16(Ab + (size_t)(c * 8 + l8) * rs + k0 * 2 + lb, (char*)As + c * 1024);
      gload16(Bb + (size_t)(c * 8 + l8) * rs + k0 * 2 + lb, (char*)Bs + c * 1024);
    }
    asm volatile("s_waitcnt vmcnt(0)" ::: "memory");
    __syncthreads();
#pragma unroll
    for (int ks = 0; ks < 2; ++ks) {
      bf16x8 af[4], bfr[4];
#pragma unroll
      for (int mf = 0; mf < 4; ++mf)
        af[mf] = ldb8(As + (wr * 64 + mf * 16 + lane16) * 64 + ks * 32 + lgrp * 8);
#pragma unroll
      for (int nf = 0; nf < 4; ++nf)
        bfr[nf] = ldb8(Bs + (wc * 64 + nf * 16 + lane16) * 64 + ks * 32 + lgrp * 8);
#pragma unroll
      for (int mf = 0; mf < 4; ++mf)
#pragma unroll
        for (int nf = 0; nf < 4; ++nf)
          acc[mf][nf] = mfma16(af[mf], bfr[nf], acc[mf][nf]);
    }
    __syncthreads();
  }

#pragma unroll
  for (int mf = 0; mf < 4; ++mf) {
    int row = m0 + wr * 64 + mf * 16 + lgrp * 4;
#pragma unroll
    for (int nf = 0; nf < 4; ++nf) {
      int col = n0 + wc * 64 + nf * 16 + lane16;
      if (MODE == 1) {
        float* o = (float*)OUT;
#pragma unroll
        for (int i = 0; i < 4; ++i) {
          size_t idx = (size_t)(row + i) * N + col;
          o[idx] = acc[mf][nf][i] + RES[idx];
        }
      } else if (MODE == 2) {
        unsigned short* o = (unsigned short*)OUT;
#pragma unroll
        for (int i = 0; i < 4; ++i)
          o[(size_t)(row + i) * N + col] = f2bf(gelu_t(acc[mf][nf][i]));
      } else {
        int bI = row >> 11, tI = row & 2047;
        if (col < 1024) {
          int hh = col >> 6, dd = col & 63;
          unsigned short* dst = Qo + (size_t)(bI * 16 + hh) * 2048 * 64;
#pragma unroll
          for (int i = 0; i < 4; ++i)
            dst[(size_t)(tI + i) * 64 + dd] = f2bf(acc[mf][nf][i]);
        } else if (col < 2048) {
          int cc = col - 1024;
          int hh = cc >> 6, dd = cc & 63;
          unsigned short* dst = Ko + (size_t)(bI * 16 + hh) * 2048 * 64;
#pragma unroll
          for (int i = 0; i < 4; ++i)
            dst[(size_t)(tI + i) * 64 + dd] = f2bf(acc[mf][nf][i]);
        } else {
          int cc = col - 2048;
          int hh = cc >> 6, dd = cc & 63;
          u16x4 pk;
#pragma unroll
          for (int i = 0; i < 4; ++i) pk[i] = f2bf(acc[mf][nf][i]);
          *(u16x4*)(VT + ((size_t)(bI * 16 + hh) * 64 + dd) * 2048 + tI) = pk;
        }
      }
    }
  }
}

// ---------------- causal flash attention -------------------------------------------------
// Q,K: [B*H][T][64] bf16; VT: [B*H][64][T] bf16; O: [B*T][1024] bf16
__global__ __launch_bounds__(256) void attn_kernel(const unsigned short* __restrict__ Q,
                                                   const unsigned short* __restrict__ Kb,
                                                   const unsigned short* __restrict__ VT,
                                                   unsigned short* __restrict__ O) {
  __shared__ __align__(16) unsigned short Ks[64 * 64];
  __shared__ __align__(16) unsigned short Vs[64 * 64];
  __shared__ __align__(16) unsigned short Ps[4][16 * 64];
  const int T = 2048;
  const int q0 = blockIdx.x * 64;
  const int bh = blockIdx.y;
  const int tid = threadIdx.x, lane = tid & 63;
  const int wid = __builtin_amdgcn_readfirstlane(tid >> 6);
  const int lane16 = lane & 15, lgrp = lane >> 4;
  const int l8 = lane >> 3, lb = (lane & 7) * 16;

  const int qrow = q0 + wid * 16 + lane16;
  const unsigned short* qp = Q + ((size_t)bh * T + qrow) * 64;
  bf16x8 qf[2];
  qf[0] = ldb8(qp + lgrp * 8);
  qf[1] = ldb8(qp + 32 + lgrp * 8);

  const char* kg = (const char*)(Kb + (size_t)bh * T * 64);
  const char* vg = (const char*)(VT + (size_t)bh * 64 * T);

  f32x4 acc_o[4] = {};
  float m_run = -1e30f, l_run = 0.f;

  const int nkv = q0 / 64 + 1;
  for (int kt = 0; kt < nkv; ++kt) {
    const int kv0 = kt * 64;
#pragma unroll
    for (int i = 0; i < 2; ++i) {
      int c = wid * 2 + i;
      gload16(kg + (size_t)(kv0 + c * 8 + l8) * 128 + lb, (char*)Ks + c * 1024);
      gload16(vg + (size_t)(c * 8 + l8) * (T * 2) + kv0 * 2 + lb, (char*)Vs + c * 1024);
    }
    asm volatile("s_waitcnt vmcnt(0)" ::: "memory");
    __syncthreads();

    // S^T = K * Q^T  (rows = kv, cols = q)
    f32x4 accs[4] = {};
#pragma unroll
    for (int kvf = 0; kvf < 4; ++kvf)
#pragma unroll
      for (int c = 0; c < 2; ++c) {
        bf16x8 kf = ldb8(Ks + (kvf * 16 + lane16) * 64 + c * 32 + lgrp * 8);
        accs[kvf] = mfma16(kf, qf[c], accs[kvf]);
      }

    float p[16];
    float tmax = -1e30f;
#pragma unroll
    for (int kvf = 0; kvf < 4; ++kvf)
#pragma unroll
      for (int i = 0; i < 4; ++i) {
        int kv = kv0 + kvf * 16 + lgrp * 4 + i;
        float sv = accs[kvf][i] * 0.125f;
        if (kv > qrow) sv = -1e30f;
        p[kvf * 4 + i] = sv;
        tmax = fmaxf(tmax, sv);
      }
    tmax = fmaxf(tmax, __shfl_xor(tmax, 16));
    tmax = fmaxf(tmax, __shfl_xor(tmax, 32));
    float m_new = fmaxf(m_run, tmax);
    float corr = __expf(m_run - m_new);
    float psum = 0.f;
#pragma unroll
    for (int j = 0; j < 16; ++j) { p[j] = __expf(p[j] - m_new); psum += p[j]; }
    psum += __shfl_xor(psum, 16);
    psum += __shfl_xor(psum, 32);
    l_run = l_run * corr + psum;
    m_run = m_new;
    float cf0 = __shfl(corr, lgrp * 4 + 0);
    float cf1 = __shfl(corr, lgrp * 4 + 1);
    float cf2 = __shfl(corr, lgrp * 4 + 2);
    float cf3 = __shfl(corr, lgrp * 4 + 3);
#pragma unroll
    for (int df = 0; df < 4; ++df) {
      acc_o[df][0] *= cf0; acc_o[df][1] *= cf1;
      acc_o[df][2] *= cf2; acc_o[df][3] *= cf3;
    }
#pragma unroll
    for (int kvf = 0; kvf < 4; ++kvf) {
      u16x4 pk;
#pragma unroll
      for (int i = 0; i < 4; ++i) pk[i] = f2bf(p[kvf * 4 + i]);
      *(u16x4*)(&Ps[wid][lane16 * 64 + kvf * 16 + lgrp * 4]) = pk;
    }
#pragma unroll
    for (int c = 0; c < 2; ++c) {
      bf16x8 pf = ldb8(&Ps[wid][lane16 * 64 + c * 32 + lgrp * 8]);
#pragma unroll
      for (int df = 0; df < 4; ++df) {
        bf16x8 vf = ldb8(Vs + (df * 16 + lane16) * 64 + c * 32 + lgrp * 8);
        acc_o[df] = mfma16(pf, vf, acc_o[df]);
      }
    }
    __syncthreads();
  }

  float il = 1.f / l_run;
  float f0 = __shfl(il, lgrp * 4 + 0);
  float f1 = __shfl(il, lgrp * 4 + 1);
  float f2 = __shfl(il, lgrp * 4 + 2);
  float f3 = __shfl(il, lgrp * 4 + 3);
  const int b = bh >> 4, h = bh & 15;
#pragma unroll
  for (int df = 0; df < 4; ++df) {
    int col = h * 64 + df * 16 + lane16;
    size_t base = ((size_t)(b * T + q0 + wid * 16 + lgrp * 4)) * 1024 + col;
    O[base] = f2bf(acc_o[df][0] * f0);
    O[base + 1024] = f2bf(acc_o[df][1] * f1);
    O[base + 2048] = f2bf(acc_o[df][2] * f2);
    O[base + 3072] = f2bf(acc_o[df][3] * f3);
  }
}

// ---------------- launcher ---------------------------------------------------------------
extern "C" void kernel_launch(void* const* d_in, const int* in_sizes, int n_in,
                              void* d_out, int out_size, void* d_ws, size_t ws_size,
                              hipStream_t stream) {
  (void)in_sizes; (void)n_in; (void)out_size; (void)ws_size;
  const float* x    = (const float*)d_in[0];
  const float* ln1w = (const float*)d_in[1];
  const float* ln1b = (const float*)d_in[2];
  const float* ln2w = (const float*)d_in[3];
  const float* ln2b = (const float*)d_in[4];
  const float* wqkv = (const float*)d_in[5];
  const float* wprj = (const float*)d_in[6];
  const float* wff1 = (const float*)d_in[7];
  const float* wff2 = (const float*)d_in[8];
  float* out = (float*)d_out;
  char* ws = (char*)d_ws;

  unsigned short* h      = (unsigned short*)(ws + 0);
  unsigned short* wqkvT  = (unsigned short*)(ws + 8388608);
  unsigned short* wprjT  = (unsigned short*)(ws + 14680064);
  unsigned short* wff1T  = (unsigned short*)(ws + 16777216);
  unsigned short* wff2T  = (unsigned short*)(ws + 25165824);
  unsigned short* qb     = (unsigned short*)(ws + 33554432);
  unsigned short* kb     = (unsigned short*)(ws + 41943040);
  unsigned short* vT     = (unsigned short*)(ws + 50331648);
  unsigned short* ob     = (unsigned short*)(ws + 58720256);
  unsigned short* h2     = (unsigned short*)(ws + 67108864);
  unsigned short* a1     = (unsigned short*)(ws + 75497472);

  // weight convert+transpose: out[C][R] = in[R][C]^T
  tconv_kernel<<<dim3(48, 16), 256, 0, stream>>>(wqkv, wqkvT, 1024, 3072);
  tconv_kernel<<<dim3(16, 16), 256, 0, stream>>>(wprj, wprjT, 1024, 1024);
  tconv_kernel<<<dim3(64, 16), 256, 0, stream>>>(wff1, wff1T, 1024, 4096);
  tconv_kernel<<<dim3(16, 64), 256, 0, stream>>>(wff2, wff2T, 4096, 1024);

  // LN1
  ln_kernel<<<4096, 256, 0, stream>>>(x, ln1w, ln1b, h);
  // QKV projection
  gemm_kernel<0><<<dim3(24, 32), 256, 0, stream>>>(h, wqkvT, nullptr, nullptr,
                                                   qb, kb, vT, 4096, 3072, 1024);
  // attention
  attn_kernel<<<dim3(32, 32), 256, 0, stream>>>(qb, kb, vT, ob);
  // out-proj + residual (fp32)
  gemm_kernel<1><<<dim3(8, 32), 256, 0, stream>>>(ob, wprjT, x, out,
                                                  nullptr, nullptr, nullptr, 4096, 1024, 1024);
  // LN2
  ln_kernel<<<4096, 256, 0, stream>>>(out, ln2w, ln2b, h2);
  // FF1 + GELU
  gemm_kernel<2><<<dim3(32, 32), 256, 0, stream>>>(h2, wff1T, nullptr, a1,
                                                   nullptr, nullptr, nullptr, 4096, 4096, 1024);
  // FF2 + residual (fp32)
  gemm_kernel<1><<<dim3(8, 32), 256, 0, stream>>>(a1, wff2T, out, out,
                                                  nullptr, nullptr, nullptr, 4096, 1024, 4096);
}

// Round 2
// 429.164 us; speedup vs baseline: 1.1375x; 1.1375x over previous
//
#include <hip/hip_runtime.h>

typedef __attribute__((ext_vector_type(8))) __bf16 bf16x8;
typedef __attribute__((ext_vector_type(8))) unsigned short u16x8;
typedef __attribute__((ext_vector_type(4))) unsigned short u16x4;
typedef __attribute__((ext_vector_type(4))) float f32x4;

__device__ __forceinline__ unsigned short f2bf(float f) {
  union { float f; unsigned int u; } v; v.f = f;
  unsigned int r = v.u + 0x7fffu + ((v.u >> 16) & 1u);
  return (unsigned short)(r >> 16);
}

__device__ __forceinline__ bf16x8 ldb8(const unsigned short* p) {
  u16x8 u = *(const u16x8*)p;
  return __builtin_bit_cast(bf16x8, u);
}

__device__ __forceinline__ f32x4 mfma16(bf16x8 a, bf16x8 b, f32x4 c) {
  return __builtin_amdgcn_mfma_f32_16x16x32_bf16(a, b, c, 0, 0, 0);
}

__device__ __forceinline__ void gload16(const void* g, void* l) {
  __builtin_amdgcn_global_load_lds(
      (const __attribute__((address_space(1))) void*)g,
      (__attribute__((address_space(3))) void*)l, 16, 0, 0);
}

__device__ __forceinline__ float gelu_t(float x) {
  float u = x * (0.7978845608028654f * (1.0f + 0.044715f * x * x));
  return 0.5f * x * (1.0f + u / (1.0f + fabsf(u)));
}

// ---------------- transpose + fp32->bf16 convert: out[C][R] = bf16(in[R][C]) --------------
__global__ __launch_bounds__(256) void tconv_kernel(const float* __restrict__ in,
                                                    unsigned short* __restrict__ out,
                                                    int R, int C) {
  __shared__ unsigned short tile[64][68];
  int r0 = blockIdx.y * 64, c0 = blockIdx.x * 64;
  int tx = threadIdx.x & 63, tg = threadIdx.x >> 6;
  for (int rr = tg; rr < 64; rr += 4)
    tile[tx][rr] = f2bf(in[(size_t)(r0 + rr) * C + c0 + tx]);
  __syncthreads();
  for (int cc = tg; cc < 64; cc += 4)
    out[(size_t)(c0 + cc) * R + r0 + tx] = tile[cc][tx];
}

// ---------------- batched V transpose: VT[bh][d][t] = V[bh][t][d] ------------------------
__global__ __launch_bounds__(256) void vtrans_kernel(const unsigned short* __restrict__ V,
                                                     unsigned short* __restrict__ VT) {
  __shared__ unsigned short tile[64][68];
  int bh = blockIdx.y;
  int t0 = blockIdx.x * 64;
  const unsigned short* in = V + (size_t)bh * 2048 * 64;
  unsigned short* out = VT + (size_t)bh * 64 * 2048;
  int tx = threadIdx.x & 63, tg = threadIdx.x >> 6;
  for (int rr = tg; rr < 64; rr += 4)
    tile[tx][rr] = in[(size_t)(t0 + rr) * 64 + tx];
  __syncthreads();
  for (int dd = tg; dd < 64; dd += 4)
    out[(size_t)dd * 2048 + t0 + tx] = tile[dd][tx];
}

// ---------------- LayerNorm: one block per row of 1024, bf16 out -------------------------
__global__ __launch_bounds__(256) void ln_kernel(const float* __restrict__ X,
                                                 const float* __restrict__ W,
                                                 const float* __restrict__ Bv,
                                                 unsigned short* __restrict__ H) {
  int row = blockIdx.x;
  int t = threadIdx.x;
  float4 v = ((const float4*)(X + (size_t)row * 1024))[t];
  float s = v.x + v.y + v.z + v.w;
  float s2 = v.x * v.x + v.y * v.y + v.z * v.z + v.w * v.w;
#pragma unroll
  for (int m = 32; m >= 1; m >>= 1) { s += __shfl_xor(s, m); s2 += __shfl_xor(s2, m); }
  __shared__ float red[8];
  if ((t & 63) == 0) { red[t >> 6] = s; red[4 + (t >> 6)] = s2; }
  __syncthreads();
  s = red[0] + red[1] + red[2] + red[3];
  s2 = red[4] + red[5] + red[6] + red[7];
  float mean = s * (1.f / 1024.f);
  float var = fmaxf(s2 * (1.f / 1024.f) - mean * mean, 0.f);
  float rs = rsqrtf(var + 1e-5f);
  float4 w4 = ((const float4*)W)[t];
  float4 b4 = ((const float4*)Bv)[t];
  u16x4 o;
  o[0] = f2bf((v.x - mean) * rs * w4.x + b4.x);
  o[1] = f2bf((v.y - mean) * rs * w4.y + b4.y);
  o[2] = f2bf((v.z - mean) * rs * w4.z + b4.z);
  o[3] = f2bf((v.w - mean) * rs * w4.w + b4.w);
  *(u16x4*)(H + (size_t)row * 1024 + t * 4) = o;
}

// ---------------- GEMM: C[M][N] = A[M][K] * B_T[N][K]^T, bf16 in, MFMA ------------------
// MODE 0: qkv epilogue (scatter Q,K,V to [B,H,T,64] coalesced)
// MODE 1: fp32 out = acc + RES
// MODE 2: bf16 out = gelu(acc)
template <int MODE>
__global__ __launch_bounds__(256) void gemm_kernel(
    const unsigned short* __restrict__ A, const unsigned short* __restrict__ B,
    const float* __restrict__ RES, void* __restrict__ OUT,
    unsigned short* __restrict__ Qo, unsigned short* __restrict__ Ko,
    unsigned short* __restrict__ Vo, int M, int N, int K) {
  __shared__ __align__(16) unsigned short As[128 * 64];
  __shared__ __align__(16) unsigned short Bs[128 * 64];
  const int tid = threadIdx.x;
  const int lane = tid & 63;
  const int wid = __builtin_amdgcn_readfirstlane(tid >> 6);
  const int lane16 = lane & 15, lgrp = lane >> 4;
  const int l8 = lane >> 3;
  const int lb = (lane & 7) * 16;
  const int m0 = blockIdx.y * 128, n0 = blockIdx.x * 128;
  const int wr = wid >> 1, wc = wid & 1;

  f32x4 acc[4][4] = {};

  const char* Ab = (const char*)A + (size_t)m0 * K * 2;
  const char* Bb = (const char*)B + (size_t)n0 * K * 2;
  const size_t rs = (size_t)K * 2;

  for (int k0 = 0; k0 < K; k0 += 64) {
#pragma unroll
    for (int i = 0; i < 4; ++i) {
      int c = wid * 4 + i;
      gload16(Ab + (size_t)(c * 8 + l8) * rs + k0 * 2 + lb, (char*)As + c * 1024);
      gload16(Bb + (size_t)(c * 8 + l8) * rs + k0 * 2 + lb, (char*)Bs + c * 1024);
    }
    asm volatile("s_waitcnt vmcnt(0)" ::: "memory");
    __syncthreads();
#pragma unroll
    for (int ks = 0; ks < 2; ++ks) {
      bf16x8 af[4], bfr[4];
#pragma unroll
      for (int mf = 0; mf < 4; ++mf)
        af[mf] = ldb8(As + (wr * 64 + mf * 16 + lane16) * 64 + ks * 32 + lgrp * 8);
#pragma unroll
      for (int nf = 0; nf < 4; ++nf)
        bfr[nf] = ldb8(Bs + (wc * 64 + nf * 16 + lane16) * 64 + ks * 32 + lgrp * 8);
#pragma unroll
      for (int mf = 0; mf < 4; ++mf)
#pragma unroll
        for (int nf = 0; nf < 4; ++nf)
          acc[mf][nf] = mfma16(af[mf], bfr[nf], acc[mf][nf]);
    }
    __syncthreads();
  }

#pragma unroll
  for (int mf = 0; mf < 4; ++mf) {
    int row = m0 + wr * 64 + mf * 16 + lgrp * 4;
#pragma unroll
    for (int nf = 0; nf < 4; ++nf) {
      int col = n0 + wc * 64 + nf * 16 + lane16;
      if (MODE == 1) {
        float* o = (float*)OUT;
#pragma unroll
        for (int i = 0; i < 4; ++i) {
          size_t idx = (size_t)(row + i) * N + col;
          o[idx] = acc[mf][nf][i] + RES[idx];
        }
      } else if (MODE == 2) {
        unsigned short* o = (unsigned short*)OUT;
#pragma unroll
        for (int i = 0; i < 4; ++i)
          o[(size_t)(row + i) * N + col] = f2bf(gelu_t(acc[mf][nf][i]));
      } else {
        int bI = row >> 11, tI = row & 2047;
        unsigned short* dst;
        int dd;
        if (col < 1024) {
          dst = Qo + (size_t)(bI * 16 + (col >> 6)) * 2048 * 64;
          dd = col & 63;
        } else if (col < 2048) {
          int cc = col - 1024;
          dst = Ko + (size_t)(bI * 16 + (cc >> 6)) * 2048 * 64;
          dd = cc & 63;
        } else {
          int cc = col - 2048;
          dst = Vo + (size_t)(bI * 16 + (cc >> 6)) * 2048 * 64;
          dd = cc & 63;
        }
#pragma unroll
        for (int i = 0; i < 4; ++i)
          dst[(size_t)(tI + i) * 64 + dd] = f2bf(acc[mf][nf][i]);
      }
    }
  }
}

// ---------------- causal flash attention -------------------------------------------------
// Q,K: [B*H][T][64] bf16; VT: [B*H][64][T] bf16; O: [B*T][1024] bf16
// QBLK=128 (4 waves x 32 rows), KVBLK=64. XOR-swizzled LDS (K,V via pre-swizzled
// global_load_lds source; P via swizzled write+read). Heavy tiles dispatch first.
__global__ __launch_bounds__(256) void attn_kernel(const unsigned short* __restrict__ Q,
                                                   const unsigned short* __restrict__ Kb,
                                                   const unsigned short* __restrict__ VT,
                                                   unsigned short* __restrict__ O) {
  __shared__ __align__(16) unsigned short Ks[64 * 64];
  __shared__ __align__(16) unsigned short Vs[64 * 64];
  __shared__ __align__(16) unsigned short Ps[4][32 * 64];
  const int T = 2048;
  const int q0 = ((int)gridDim.x - 1 - (int)blockIdx.x) * 128;
  const int bh = blockIdx.y;
  const int tid = threadIdx.x, lane = tid & 63;
  const int wid = __builtin_amdgcn_readfirstlane(tid >> 6);
  const int lane16 = lane & 15, lgrp = lane >> 4;
  const int l8 = lane >> 3;
  const int swz = ((lane & 7) ^ (l8 & 7)) << 4;  // pre-swizzled global source chunk

  const int qbase = q0 + wid * 32;
  bf16x8 qf[2][2];
#pragma unroll
  for (int qc = 0; qc < 2; ++qc) {
    const unsigned short* qp = Q + ((size_t)bh * T + qbase + qc * 16 + lane16) * 64;
    qf[qc][0] = ldb8(qp + lgrp * 8);
    qf[qc][1] = ldb8(qp + 32 + lgrp * 8);
  }

  const char* kg = (const char*)(Kb + (size_t)bh * T * 64);
  const char* vg = (const char*)(VT + (size_t)bh * 64 * T);
  char* PsB = (char*)&Ps[wid][0];

  f32x4 acc_o[2][4] = {};
  float m_run[2] = {-1e30f, -1e30f};
  float l_run[2] = {0.f, 0.f};

  const int nkv = q0 / 64 + 2;
  for (int kt = 0; kt < nkv; ++kt) {
    const int kv0 = kt * 64;
#pragma unroll
    for (int i = 0; i < 2; ++i) {
      int c = wid * 2 + i;
      gload16(kg + (size_t)(kv0 + c * 8 + l8) * 128 + swz, (char*)Ks + c * 1024);
      gload16(vg + (size_t)(c * 8 + l8) * (T * 2) + (size_t)kv0 * 2 + swz, (char*)Vs + c * 1024);
    }
    asm volatile("s_waitcnt vmcnt(0)" ::: "memory");
    __syncthreads();

    // K,V fragments: shared across both q-frags (swizzled reads, conflict-free)
    bf16x8 kf[4][2], vf[4][2];
#pragma unroll
    for (int f = 0; f < 4; ++f)
#pragma unroll
      for (int c = 0; c < 2; ++c) {
        int row = f * 16 + lane16;
        int off = (c * 64 + lgrp * 16) ^ ((row & 7) << 4);
        kf[f][c] = ldb8((const unsigned short*)((const char*)Ks + row * 128 + off));
        vf[f][c] = ldb8((const unsigned short*)((const char*)Vs + row * 128 + off));
      }

#pragma unroll
    for (int qc = 0; qc < 2; ++qc) {
      const int qrow = qbase + qc * 16 + lane16;
      f32x4 accs[4] = {};
      __builtin_amdgcn_s_setprio(1);
#pragma unroll
      for (int kvf = 0; kvf < 4; ++kvf)
#pragma unroll
        for (int c = 0; c < 2; ++c)
          accs[kvf] = mfma16(kf[kvf][c], qf[qc][c], accs[kvf]);
      __builtin_amdgcn_s_setprio(0);

      float p[16];
      float tmax = -1e30f;
#pragma unroll
      for (int kvf = 0; kvf < 4; ++kvf)
#pragma unroll
        for (int i = 0; i < 4; ++i) {
          int kv = kv0 + kvf * 16 + lgrp * 4 + i;
          float sv = accs[kvf][i] * 0.125f;
          sv = (kv > qrow) ? -1e30f : sv;
          p[kvf * 4 + i] = sv;
          tmax = fmaxf(tmax, sv);
        }
      tmax = fmaxf(tmax, __shfl_xor(tmax, 16));
      tmax = fmaxf(tmax, __shfl_xor(tmax, 32));
      float m_new = fmaxf(m_run[qc], tmax);
      float corr = __expf(m_run[qc] - m_new);
      float psum = 0.f;
#pragma unroll
      for (int j = 0; j < 16; ++j) { p[j] = __expf(p[j] - m_new); psum += p[j]; }
      psum += __shfl_xor(psum, 16);
      psum += __shfl_xor(psum, 32);
      l_run[qc] = l_run[qc] * corr + psum;
      m_run[qc] = m_new;
      float cf0 = __shfl(corr, lgrp * 4 + 0);
      float cf1 = __shfl(corr, lgrp * 4 + 1);
      float cf2 = __shfl(corr, lgrp * 4 + 2);
      float cf3 = __shfl(corr, lgrp * 4 + 3);
#pragma unroll
      for (int df = 0; df < 4; ++df) {
        acc_o[qc][df][0] *= cf0; acc_o[qc][df][1] *= cf1;
        acc_o[qc][df][2] *= cf2; acc_o[qc][df][3] *= cf3;
      }
      const int prow = qc * 16 + lane16;
#pragma unroll
      for (int kvf = 0; kvf < 4; ++kvf) {
        u16x4 pk;
#pragma unroll
        for (int i = 0; i < 4; ++i) pk[i] = f2bf(p[kvf * 4 + i]);
        *(u16x4*)(PsB + prow * 128 + ((kvf * 32 + lgrp * 8) ^ ((prow & 7) << 4))) = pk;
      }
      bf16x8 pf[2];
#pragma unroll
      for (int c = 0; c < 2; ++c)
        pf[c] = ldb8((const unsigned short*)(PsB + prow * 128 +
                     ((c * 64 + lgrp * 16) ^ ((prow & 7) << 4))));
      __builtin_amdgcn_s_setprio(1);
#pragma unroll
      for (int c = 0; c < 2; ++c)
#pragma unroll
        for (int df = 0; df < 4; ++df)
          acc_o[qc][df] = mfma16(pf[c], vf[df][c], acc_o[qc][df]);
      __builtin_amdgcn_s_setprio(0);
    }
    __syncthreads();
  }

  const int b = bh >> 4, hh = bh & 15;
#pragma unroll
  for (int qc = 0; qc < 2; ++qc) {
    float il = 1.f / l_run[qc];
    float f0 = __shfl(il, lgrp * 4 + 0);
    float f1 = __shfl(il, lgrp * 4 + 1);
    float f2 = __shfl(il, lgrp * 4 + 2);
    float f3 = __shfl(il, lgrp * 4 + 3);
#pragma unroll
    for (int df = 0; df < 4; ++df) {
      int col = hh * 64 + df * 16 + lane16;
      size_t base = ((size_t)(b * T + qbase + qc * 16 + lgrp * 4)) * 1024 + col;
      O[base] = f2bf(acc_o[qc][df][0] * f0);
      O[base + 1024] = f2bf(acc_o[qc][df][1] * f1);
      O[base + 2048] = f2bf(acc_o[qc][df][2] * f2);
      O[base + 3072] = f2bf(acc_o[qc][df][3] * f3);
    }
  }
}

// ---------------- launcher ---------------------------------------------------------------
extern "C" void kernel_launch(void* const* d_in, const int* in_sizes, int n_in,
                              void* d_out, int out_size, void* d_ws, size_t ws_size,
                              hipStream_t stream) {
  (void)in_sizes; (void)n_in; (void)out_size; (void)ws_size;
  const float* x    = (const float*)d_in[0];
  const float* ln1w = (const float*)d_in[1];
  const float* ln1b = (const float*)d_in[2];
  const float* ln2w = (const float*)d_in[3];
  const float* ln2b = (const float*)d_in[4];
  const float* wqkv = (const float*)d_in[5];
  const float* wprj = (const float*)d_in[6];
  const float* wff1 = (const float*)d_in[7];
  const float* wff2 = (const float*)d_in[8];
  float* out = (float*)d_out;
  char* ws = (char*)d_ws;

  unsigned short* h      = (unsigned short*)(ws + 0);
  unsigned short* wqkvT  = (unsigned short*)(ws + 8388608);
  unsigned short* wprjT  = (unsigned short*)(ws + 14680064);
  unsigned short* wff1T  = (unsigned short*)(ws + 16777216);
  unsigned short* wff2T  = (unsigned short*)(ws + 25165824);
  unsigned short* qb     = (unsigned short*)(ws + 33554432);
  unsigned short* kb     = (unsigned short*)(ws + 41943040);
  unsigned short* vT     = (unsigned short*)(ws + 50331648);
  unsigned short* ob     = (unsigned short*)(ws + 58720256);
  unsigned short* h2     = (unsigned short*)(ws + 67108864);  // also Vo (dead before LN2)
  unsigned short* a1     = (unsigned short*)(ws + 75497472);
  unsigned short* vo     = h2;

  // weight convert+transpose: out[C][R] = in[R][C]^T
  tconv_kernel<<<dim3(48, 16), 256, 0, stream>>>(wqkv, wqkvT, 1024, 3072);
  tconv_kernel<<<dim3(16, 16), 256, 0, stream>>>(wprj, wprjT, 1024, 1024);
  tconv_kernel<<<dim3(64, 16), 256, 0, stream>>>(wff1, wff1T, 1024, 4096);
  tconv_kernel<<<dim3(16, 64), 256, 0, stream>>>(wff2, wff2T, 4096, 1024);

  // LN1
  ln_kernel<<<4096, 256, 0, stream>>>(x, ln1w, ln1b, h);
  // QKV projection (coalesced Q,K,V stores)
  gemm_kernel<0><<<dim3(24, 32), 256, 0, stream>>>(h, wqkvT, nullptr, nullptr,
                                                   qb, kb, vo, 4096, 3072, 1024);
  // V transpose to [B,H,64,T]
  vtrans_kernel<<<dim3(32, 32), 256, 0, stream>>>(vo, vT);
  // attention
  attn_kernel<<<dim3(16, 32), 256, 0, stream>>>(qb, kb, vT, ob);
  // out-proj + residual (fp32)
  gemm_kernel<1><<<dim3(8, 32), 256, 0, stream>>>(ob, wprjT, x, out,
                                                  nullptr, nullptr, nullptr, 4096, 1024, 1024);
  // LN2
  ln_kernel<<<4096, 256, 0, stream>>>(out, ln2w, ln2b, h2);
  // FF1 + GELU
  gemm_kernel<2><<<dim3(32, 32), 256, 0, stream>>>(h2, wff1T, nullptr, a1,
                                                   nullptr, nullptr, nullptr, 4096, 4096, 1024);
  // FF2 + residual (fp32)
  gemm_kernel<1><<<dim3(8, 32), 256, 0, stream>>>(a1, wff2T, out, out,
                                                  nullptr, nullptr, nullptr, 4096, 1024, 4096);
}

// Round 4
// 426.125 us; speedup vs baseline: 1.1456x; 1.0071x over previous
//
#include <hip/hip_runtime.h>

typedef __attribute__((ext_vector_type(8))) __bf16 bf16x8;
typedef __attribute__((ext_vector_type(8))) unsigned short u16x8;
typedef __attribute__((ext_vector_type(4))) unsigned short u16x4;
typedef __attribute__((ext_vector_type(4))) float f32x4;

__device__ __forceinline__ unsigned short f2bf(float f) {
  return __builtin_bit_cast(unsigned short, (__bf16)f);
}

__device__ __forceinline__ bf16x8 ldb8(const unsigned short* p) {
  u16x8 u = *(const u16x8*)p;
  return __builtin_bit_cast(bf16x8, u);
}

__device__ __forceinline__ f32x4 mfma16(bf16x8 a, bf16x8 b, f32x4 c) {
  return __builtin_amdgcn_mfma_f32_16x16x32_bf16(a, b, c, 0, 0, 0);
}

__device__ __forceinline__ void gload16(const void* g, void* l) {
  __builtin_amdgcn_global_load_lds(
      (const __attribute__((address_space(1))) void*)g,
      (__attribute__((address_space(3))) void*)l, 16, 0, 0);
}

__device__ __forceinline__ float gelu_t(float x) {
  float u = x * (0.7978845608028654f * (1.0f + 0.044715f * x * x));
  return 0.5f * x * (1.0f + u / (1.0f + fabsf(u)));
}

// ---------------- transpose + fp32->bf16 convert: out[C][R] = bf16(in[R][C]) --------------
__global__ __launch_bounds__(256) void tconv_kernel(const float* __restrict__ in,
                                                    unsigned short* __restrict__ out,
                                                    int R, int C) {
  __shared__ unsigned short tile[64][68];
  int r0 = blockIdx.y * 64, c0 = blockIdx.x * 64;
  int tx = threadIdx.x & 63, tg = threadIdx.x >> 6;
  for (int rr = tg; rr < 64; rr += 4)
    tile[tx][rr] = f2bf(in[(size_t)(r0 + rr) * C + c0 + tx]);
  __syncthreads();
  for (int cc = tg; cc < 64; cc += 4)
    out[(size_t)(c0 + cc) * R + r0 + tx] = tile[cc][tx];
}

// ---------------- batched V transpose: VT[bh][d][t] = V[bh][t][d] ------------------------
__global__ __launch_bounds__(256) void vtrans_kernel(const unsigned short* __restrict__ V,
                                                     unsigned short* __restrict__ VT) {
  __shared__ unsigned short tile[64][68];
  int bh = blockIdx.y;
  int t0 = blockIdx.x * 64;
  const unsigned short* in = V + (size_t)bh * 2048 * 64;
  unsigned short* out = VT + (size_t)bh * 64 * 2048;
  int tx = threadIdx.x & 63, tg = threadIdx.x >> 6;
  for (int rr = tg; rr < 64; rr += 4)
    tile[tx][rr] = in[(size_t)(t0 + rr) * 64 + tx];
  __syncthreads();
  for (int dd = tg; dd < 64; dd += 4)
    out[(size_t)dd * 2048 + t0 + tx] = tile[dd][tx];
}

// ---------------- LayerNorm: one block per row of 1024, bf16 out -------------------------
__global__ __launch_bounds__(256) void ln_kernel(const float* __restrict__ X,
                                                 const float* __restrict__ W,
                                                 const float* __restrict__ Bv,
                                                 unsigned short* __restrict__ H) {
  int row = blockIdx.x;
  int t = threadIdx.x;
  float4 v = ((const float4*)(X + (size_t)row * 1024))[t];
  float s = v.x + v.y + v.z + v.w;
  float s2 = v.x * v.x + v.y * v.y + v.z * v.z + v.w * v.w;
#pragma unroll
  for (int m = 32; m >= 1; m >>= 1) { s += __shfl_xor(s, m); s2 += __shfl_xor(s2, m); }
  __shared__ float red[8];
  if ((t & 63) == 0) { red[t >> 6] = s; red[4 + (t >> 6)] = s2; }
  __syncthreads();
  s = red[0] + red[1] + red[2] + red[3];
  s2 = red[4] + red[5] + red[6] + red[7];
  float mean = s * (1.f / 1024.f);
  float var = fmaxf(s2 * (1.f / 1024.f) - mean * mean, 0.f);
  float rs = rsqrtf(var + 1e-5f);
  float4 w4 = ((const float4*)W)[t];
  float4 b4 = ((const float4*)Bv)[t];
  u16x4 o;
  o[0] = f2bf((v.x - mean) * rs * w4.x + b4.x);
  o[1] = f2bf((v.y - mean) * rs * w4.y + b4.y);
  o[2] = f2bf((v.z - mean) * rs * w4.z + b4.z);
  o[3] = f2bf((v.w - mean) * rs * w4.w + b4.w);
  *(u16x4*)(H + (size_t)row * 1024 + t * 4) = o;
}

// ---------------- GEMM: C[M][N] = A[M][K] * B_T[N][K]^T, bf16 in, MFMA ------------------
// MODE 0: qkv epilogue (scatter Q,K,V to [B,H,T,64] coalesced)
// MODE 1: fp32 out = acc + RES
// MODE 2: bf16 out = gelu(acc)
// DBUF: double-buffered LDS with issue-early staging (for 1-block/CU grids)
template <int MODE, bool DBUF>
__global__ __launch_bounds__(256) void gemm_kernel(
    const unsigned short* __restrict__ A, const unsigned short* __restrict__ B,
    const float* __restrict__ RES, void* __restrict__ OUT,
    unsigned short* __restrict__ Qo, unsigned short* __restrict__ Ko,
    unsigned short* __restrict__ Vo, int M, int N, int K) {
  __shared__ __align__(16) unsigned short As[DBUF ? 2 : 1][128 * 64];
  __shared__ __align__(16) unsigned short Bs[DBUF ? 2 : 1][128 * 64];
  const int tid = threadIdx.x;
  const int lane = tid & 63;
  const int wid = __builtin_amdgcn_readfirstlane(tid >> 6);
  const int lane16 = lane & 15, lgrp = lane >> 4;
  const int l8 = lane >> 3;
  const int lb = (lane & 7) * 16;
  const int m0 = blockIdx.y * 128, n0 = blockIdx.x * 128;
  const int wr = wid >> 1, wc = wid & 1;

  f32x4 acc[4][4] = {};

  const char* Ab = (const char*)A + (size_t)m0 * K * 2;
  const char* Bb = (const char*)B + (size_t)n0 * K * 2;
  const size_t rs = (size_t)K * 2;

  auto stage = [&](int k0, int b) {
#pragma unroll
    for (int i = 0; i < 4; ++i) {
      int c = wid * 4 + i;
      gload16(Ab + (size_t)(c * 8 + l8) * rs + (size_t)k0 * 2 + lb,
              (char*)&As[0][0] + b * 16384 + c * 1024);
      gload16(Bb + (size_t)(c * 8 + l8) * rs + (size_t)k0 * 2 + lb,
              (char*)&Bs[0][0] + b * 16384 + c * 1024);
    }
  };

  const int kIt = K / 64;
  if (DBUF) stage(0, 0);

  for (int it = 0; it < kIt; ++it) {
    int cur;
    if (DBUF) {
      cur = it & 1;
      asm volatile("s_waitcnt vmcnt(0)" ::: "memory");
      __syncthreads();
      if (it + 1 < kIt) stage((it + 1) * 64, cur ^ 1);
    } else {
      cur = 0;
      stage(it * 64, 0);
      asm volatile("s_waitcnt vmcnt(0)" ::: "memory");
      __syncthreads();
    }
#pragma unroll
    for (int ks = 0; ks < 2; ++ks) {
      bf16x8 af[4], bfr[4];
#pragma unroll
      for (int mf = 0; mf < 4; ++mf)
        af[mf] = ldb8(&As[cur][(wr * 64 + mf * 16 + lane16) * 64 + ks * 32 + lgrp * 8]);
#pragma unroll
      for (int nf = 0; nf < 4; ++nf)
        bfr[nf] = ldb8(&Bs[cur][(wc * 64 + nf * 16 + lane16) * 64 + ks * 32 + lgrp * 8]);
#pragma unroll
      for (int mf = 0; mf < 4; ++mf)
#pragma unroll
        for (int nf = 0; nf < 4; ++nf)
          acc[mf][nf] = mfma16(af[mf], bfr[nf], acc[mf][nf]);
    }
    if (!DBUF) __syncthreads();
  }

#pragma unroll
  for (int mf = 0; mf < 4; ++mf) {
    int row = m0 + wr * 64 + mf * 16 + lgrp * 4;
#pragma unroll
    for (int nf = 0; nf < 4; ++nf) {
      int col = n0 + wc * 64 + nf * 16 + lane16;
      if (MODE == 1) {
        float* o = (float*)OUT;
#pragma unroll
        for (int i = 0; i < 4; ++i) {
          size_t idx = (size_t)(row + i) * N + col;
          o[idx] = acc[mf][nf][i] + RES[idx];
        }
      } else if (MODE == 2) {
        unsigned short* o = (unsigned short*)OUT;
#pragma unroll
        for (int i = 0; i < 4; ++i)
          o[(size_t)(row + i) * N + col] = f2bf(gelu_t(acc[mf][nf][i]));
      } else {
        int bI = row >> 11, tI = row & 2047;
        unsigned short* dst;
        int dd;
        if (col < 1024) {
          dst = Qo + (size_t)(bI * 16 + (col >> 6)) * 2048 * 64;
          dd = col & 63;
        } else if (col < 2048) {
          int cc = col - 1024;
          dst = Ko + (size_t)(bI * 16 + (cc >> 6)) * 2048 * 64;
          dd = cc & 63;
        } else {
          int cc = col - 2048;
          dst = Vo + (size_t)(bI * 16 + (cc >> 6)) * 2048 * 64;
          dd = cc & 63;
        }
#pragma unroll
        for (int i = 0; i < 4; ++i)
          dst[(size_t)(tI + i) * 64 + dd] = f2bf(acc[mf][nf][i]);
      }
    }
  }
}

// ---------------- causal flash attention -------------------------------------------------
// Q,K: [B*H][T][64] bf16; VT: [B*H][64][T] bf16; O: [B*T][1024] bf16
// QBLK=128 (4 waves x 32 rows), KVBLK=64, double-buffered K/V staging,
// exp2-domain softmax with defer-max, wave-uniform causal-mask branch.
__global__ __launch_bounds__(256) void attn_kernel(const unsigned short* __restrict__ Q,
                                                   const unsigned short* __restrict__ Kb,
                                                   const unsigned short* __restrict__ VT,
                                                   unsigned short* __restrict__ O) {
  __shared__ __align__(16) unsigned short Ks[2][64 * 64];
  __shared__ __align__(16) unsigned short Vs[2][64 * 64];
  __shared__ __align__(16) unsigned short Ps[4][32 * 64];
  const int T = 2048;
  const int q0 = ((int)gridDim.x - 1 - (int)blockIdx.x) * 128;
  const int bh = blockIdx.y;
  const int tid = threadIdx.x, lane = tid & 63;
  const int wid = __builtin_amdgcn_readfirstlane(tid >> 6);
  const int lane16 = lane & 15, lgrp = lane >> 4;
  const int l8 = lane >> 3;
  const int swz = ((lane & 7) ^ (l8 & 7)) << 4;  // pre-swizzled global source chunk
  const float SCL2 = 0.18033688011112042f;       // 0.125 * log2(e)

  const int qbase = q0 + wid * 32;
  bf16x8 qf[2][2];
#pragma unroll
  for (int qc = 0; qc < 2; ++qc) {
    const unsigned short* qp = Q + ((size_t)bh * T + qbase + qc * 16 + lane16) * 64;
    qf[qc][0] = ldb8(qp + lgrp * 8);
    qf[qc][1] = ldb8(qp + 32 + lgrp * 8);
  }

  const char* kg = (const char*)(Kb + (size_t)bh * T * 64);
  const char* vg = (const char*)(VT + (size_t)bh * 64 * T);
  char* PsB = (char*)&Ps[wid][0];

  auto stage = [&](int kv0, int b) {
#pragma unroll
    for (int i = 0; i < 2; ++i) {
      int c = wid * 2 + i;
      gload16(kg + (size_t)(kv0 + c * 8 + l8) * 128 + swz,
              (char*)&Ks[0][0] + b * 8192 + c * 1024);
      gload16(vg + (size_t)(c * 8 + l8) * (T * 2) + (size_t)kv0 * 2 + swz,
              (char*)&Vs[0][0] + b * 8192 + c * 1024);
    }
  };

  f32x4 acc_o[2][4] = {};
  float m_run[2] = {-1e30f, -1e30f};
  float l_run[2] = {0.f, 0.f};

  const int nkv = q0 / 64 + 2;
  stage(0, 0);
  for (int kt = 0; kt < nkv; ++kt) {
    const int kv0 = kt * 64;
    const int cur = kt & 1;
    asm volatile("s_waitcnt vmcnt(0)" ::: "memory");
    __syncthreads();
    if (kt + 1 < nkv) stage((kt + 1) * 64, cur ^ 1);

    const char* KsB = (const char*)&Ks[0][0] + cur * 8192;
    const char* VsB = (const char*)&Vs[0][0] + cur * 8192;

    // K,V fragments: shared across both q-frags (swizzled reads, conflict-free)
    bf16x8 kf[4][2], vf[4][2];
#pragma unroll
    for (int f = 0; f < 4; ++f)
#pragma unroll
      for (int c = 0; c < 2; ++c) {
        int row = f * 16 + lane16;
        int off = (c * 64 + lgrp * 16) ^ ((row & 7) << 4);
        kf[f][c] = ldb8((const unsigned short*)(KsB + row * 128 + off));
        vf[f][c] = ldb8((const unsigned short*)(VsB + row * 128 + off));
      }

#pragma unroll
    for (int qc = 0; qc < 2; ++qc) {
      const int qrow = qbase + qc * 16 + lane16;
      f32x4 accs[4] = {};
      __builtin_amdgcn_s_setprio(1);
#pragma unroll
      for (int kvf = 0; kvf < 4; ++kvf)
#pragma unroll
        for (int c = 0; c < 2; ++c)
          accs[kvf] = mfma16(kf[kvf][c], qf[qc][c], accs[kvf]);
      __builtin_amdgcn_s_setprio(0);

      float sc[16];
      if (kv0 + 64 <= qbase + qc * 16) {
        // fully-unmasked tile for this fragment (wave-uniform branch)
#pragma unroll
        for (int kvf = 0; kvf < 4; ++kvf)
#pragma unroll
          for (int i = 0; i < 4; ++i)
            sc[kvf * 4 + i] = accs[kvf][i] * SCL2;
      } else {
#pragma unroll
        for (int kvf = 0; kvf < 4; ++kvf)
#pragma unroll
          for (int i = 0; i < 4; ++i) {
            int kv = kv0 + kvf * 16 + lgrp * 4 + i;
            float v = accs[kvf][i] * SCL2;
            sc[kvf * 4 + i] = (kv > qrow) ? -1e30f : v;
          }
      }
      float tmax = sc[0];
#pragma unroll
      for (int j = 1; j < 16; ++j) tmax = fmaxf(tmax, sc[j]);
      tmax = fmaxf(tmax, __shfl_xor(tmax, 16));
      tmax = fmaxf(tmax, __shfl_xor(tmax, 32));
      float m_c = m_run[qc];
      if (!__all(tmax <= m_c + 8.f)) {  // defer-max (T13): rescale only on real growth
        float m_new = fmaxf(m_c, tmax);
        float corr = exp2f(m_c - m_new);
        l_run[qc] *= corr;
        float cf0 = __shfl(corr, lgrp * 4 + 0);
        float cf1 = __shfl(corr, lgrp * 4 + 1);
        float cf2 = __shfl(corr, lgrp * 4 + 2);
        float cf3 = __shfl(corr, lgrp * 4 + 3);
#pragma unroll
        for (int df = 0; df < 4; ++df) {
          acc_o[qc][df][0] *= cf0; acc_o[qc][df][1] *= cf1;
          acc_o[qc][df][2] *= cf2; acc_o[qc][df][3] *= cf3;
        }
        m_run[qc] = m_new;
        m_c = m_new;
      }
      float p[16];
      float psum = 0.f;
#pragma unroll
      for (int j = 0; j < 16; ++j) { p[j] = exp2f(sc[j] - m_c); psum += p[j]; }
      psum += __shfl_xor(psum, 16);
      psum += __shfl_xor(psum, 32);
      l_run[qc] += psum;

      const int prow = qc * 16 + lane16;
#pragma unroll
      for (int kvf = 0; kvf < 4; ++kvf) {
        u16x4 pk;
#pragma unroll
        for (int i = 0; i < 4; ++i) pk[i] = f2bf(p[kvf * 4 + i]);
        *(u16x4*)(PsB + prow * 128 + ((kvf * 32 + lgrp * 8) ^ ((prow & 7) << 4))) = pk;
      }
      bf16x8 pf[2];
#pragma unroll
      for (int c = 0; c < 2; ++c)
        pf[c] = ldb8((const unsigned short*)(PsB + prow * 128 +
                     ((c * 64 + lgrp * 16) ^ ((prow & 7) << 4))));
      __builtin_amdgcn_s_setprio(1);
#pragma unroll
      for (int c = 0; c < 2; ++c)
#pragma unroll
        for (int df = 0; df < 4; ++df)
          acc_o[qc][df] = mfma16(pf[c], vf[df][c], acc_o[qc][df]);
      __builtin_amdgcn_s_setprio(0);
    }
  }

  const int b = bh >> 4, hh = bh & 15;
#pragma unroll
  for (int qc = 0; qc < 2; ++qc) {
    float il = 1.f / l_run[qc];
    float f0 = __shfl(il, lgrp * 4 + 0);
    float f1 = __shfl(il, lgrp * 4 + 1);
    float f2 = __shfl(il, lgrp * 4 + 2);
    float f3 = __shfl(il, lgrp * 4 + 3);
#pragma unroll
    for (int df = 0; df < 4; ++df) {
      int col = hh * 64 + df * 16 + lane16;
      size_t base = ((size_t)(b * T + qbase + qc * 16 + lgrp * 4)) * 1024 + col;
      O[base] = f2bf(acc_o[qc][df][0] * f0);
      O[base + 1024] = f2bf(acc_o[qc][df][1] * f1);
      O[base + 2048] = f2bf(acc_o[qc][df][2] * f2);
      O[base + 3072] = f2bf(acc_o[qc][df][3] * f3);
    }
  }
}

// ---------------- launcher ---------------------------------------------------------------
extern "C" void kernel_launch(void* const* d_in, const int* in_sizes, int n_in,
                              void* d_out, int out_size, void* d_ws, size_t ws_size,
                              hipStream_t stream) {
  (void)in_sizes; (void)n_in; (void)out_size; (void)ws_size;
  const float* x    = (const float*)d_in[0];
  const float* ln1w = (const float*)d_in[1];
  const float* ln1b = (const float*)d_in[2];
  const float* ln2w = (const float*)d_in[3];
  const float* ln2b = (const float*)d_in[4];
  const float* wqkv = (const float*)d_in[5];
  const float* wprj = (const float*)d_in[6];
  const float* wff1 = (const float*)d_in[7];
  const float* wff2 = (const float*)d_in[8];
  float* out = (float*)d_out;
  char* ws = (char*)d_ws;

  unsigned short* h      = (unsigned short*)(ws + 0);
  unsigned short* wqkvT  = (unsigned short*)(ws + 8388608);
  unsigned short* wprjT  = (unsigned short*)(ws + 14680064);
  unsigned short* wff1T  = (unsigned short*)(ws + 16777216);
  unsigned short* wff2T  = (unsigned short*)(ws + 25165824);
  unsigned short* qb     = (unsigned short*)(ws + 33554432);
  unsigned short* kb     = (unsigned short*)(ws + 41943040);
  unsigned short* vT     = (unsigned short*)(ws + 50331648);
  unsigned short* ob     = (unsigned short*)(ws + 58720256);
  unsigned short* h2     = (unsigned short*)(ws + 67108864);  // also Vo (dead before LN2)
  unsigned short* a1     = (unsigned short*)(ws + 75497472);
  unsigned short* vo     = h2;

  // weight convert+transpose: out[C][R] = in[R][C]^T
  tconv_kernel<<<dim3(48, 16), 256, 0, stream>>>(wqkv, wqkvT, 1024, 3072);
  tconv_kernel<<<dim3(16, 16), 256, 0, stream>>>(wprj, wprjT, 1024, 1024);
  tconv_kernel<<<dim3(64, 16), 256, 0, stream>>>(wff1, wff1T, 1024, 4096);
  tconv_kernel<<<dim3(16, 64), 256, 0, stream>>>(wff2, wff2T, 4096, 1024);

  // LN1
  ln_kernel<<<4096, 256, 0, stream>>>(x, ln1w, ln1b, h);
  // QKV projection (coalesced Q,K,V stores) — 768 blocks, keep single-buffer
  gemm_kernel<0, false><<<dim3(24, 32), 256, 0, stream>>>(h, wqkvT, nullptr, nullptr,
                                                          qb, kb, vo, 4096, 3072, 1024);
  // V transpose to [B,H,64,T]
  vtrans_kernel<<<dim3(32, 32), 256, 0, stream>>>(vo, vT);
  // attention
  attn_kernel<<<dim3(16, 32), 256, 0, stream>>>(qb, kb, vT, ob);
  // out-proj + residual (fp32) — 256 blocks (1/CU): double-buffered
  gemm_kernel<1, true><<<dim3(8, 32), 256, 0, stream>>>(ob, wprjT, x, out,
                                                        nullptr, nullptr, nullptr, 4096, 1024, 1024);
  // LN2
  ln_kernel<<<4096, 256, 0, stream>>>(out, ln2w, ln2b, h2);
  // FF1 + GELU — 1024 blocks, keep single-buffer
  gemm_kernel<2, false><<<dim3(32, 32), 256, 0, stream>>>(h2, wff1T, nullptr, a1,
                                                          nullptr, nullptr, nullptr, 4096, 4096, 1024);
  // FF2 + residual (fp32) — 256 blocks (1/CU): double-buffered
  gemm_kernel<1, true><<<dim3(8, 32), 256, 0, stream>>>(a1, wff2T, out, out,
                                                        nullptr, nullptr, nullptr, 4096, 1024, 4096);
}

// Round 7
// 417.513 us; speedup vs baseline: 1.1693x; 1.0206x over previous
//
#include <hip/hip_runtime.h>

typedef __attribute__((ext_vector_type(8))) __bf16 bf16x8;
typedef __attribute__((ext_vector_type(8))) unsigned short u16x8;
typedef __attribute__((ext_vector_type(4))) unsigned short u16x4;
typedef __attribute__((ext_vector_type(4))) float f32x4;

__device__ __forceinline__ unsigned short f2bf(float f) {
  return __builtin_bit_cast(unsigned short, (__bf16)f);
}

__device__ __forceinline__ bf16x8 ldb8(const unsigned short* p) {
  u16x8 u = *(const u16x8*)p;
  return __builtin_bit_cast(bf16x8, u);
}

__device__ __forceinline__ f32x4 mfma16(bf16x8 a, bf16x8 b, f32x4 c) {
  return __builtin_amdgcn_mfma_f32_16x16x32_bf16(a, b, c, 0, 0, 0);
}

__device__ __forceinline__ void gload16(const void* g, void* l) {
  __builtin_amdgcn_global_load_lds(
      (const __attribute__((address_space(1))) void*)g,
      (__attribute__((address_space(3))) void*)l, 16, 0, 0);
}

__device__ __forceinline__ float gelu_t(float x) {
  float u = x * (0.7978845608028654f * (1.0f + 0.044715f * x * x));
  return 0.5f * x * (1.0f + u / (1.0f + fabsf(u)));
}

// ---------------- transpose + fp32->bf16 convert: out[C][R] = bf16(in[R][C]) --------------
__global__ __launch_bounds__(256) void tconv_kernel(const float* __restrict__ in,
                                                    unsigned short* __restrict__ out,
                                                    int R, int C) {
  __shared__ unsigned short tile[64][68];
  int r0 = blockIdx.y * 64, c0 = blockIdx.x * 64;
  int tx = threadIdx.x & 63, tg = threadIdx.x >> 6;
  for (int rr = tg; rr < 64; rr += 4)
    tile[tx][rr] = f2bf(in[(size_t)(r0 + rr) * C + c0 + tx]);
  __syncthreads();
  for (int cc = tg; cc < 64; cc += 4)
    out[(size_t)(c0 + cc) * R + r0 + tx] = tile[cc][tx];
}

// ---------------- batched V transpose: VT[bh][d][t] = V[bh][t][d] ------------------------
__global__ __launch_bounds__(256) void vtrans_kernel(const unsigned short* __restrict__ V,
                                                     unsigned short* __restrict__ VT) {
  __shared__ unsigned short tile[64][68];
  int bh = blockIdx.y;
  int t0 = blockIdx.x * 64;
  const unsigned short* in = V + (size_t)bh * 2048 * 64;
  unsigned short* out = VT + (size_t)bh * 64 * 2048;
  int tx = threadIdx.x & 63, tg = threadIdx.x >> 6;
  for (int rr = tg; rr < 64; rr += 4)
    tile[tx][rr] = in[(size_t)(t0 + rr) * 64 + tx];
  __syncthreads();
  for (int dd = tg; dd < 64; dd += 4)
    out[(size_t)dd * 2048 + t0 + tx] = tile[dd][tx];
}

// ---------------- LayerNorm: one block per row of 1024, bf16 out -------------------------
__global__ __launch_bounds__(256) void ln_kernel(const float* __restrict__ X,
                                                 const float* __restrict__ W,
                                                 const float* __restrict__ Bv,
                                                 unsigned short* __restrict__ H) {
  int row = blockIdx.x;
  int t = threadIdx.x;
  float4 v = ((const float4*)(X + (size_t)row * 1024))[t];
  float s = v.x + v.y + v.z + v.w;
  float s2 = v.x * v.x + v.y * v.y + v.z * v.z + v.w * v.w;
#pragma unroll
  for (int m = 32; m >= 1; m >>= 1) { s += __shfl_xor(s, m); s2 += __shfl_xor(s2, m); }
  __shared__ float red[8];
  if ((t & 63) == 0) { red[t >> 6] = s; red[4 + (t >> 6)] = s2; }
  __syncthreads();
  s = red[0] + red[1] + red[2] + red[3];
  s2 = red[4] + red[5] + red[6] + red[7];
  float mean = s * (1.f / 1024.f);
  float var = fmaxf(s2 * (1.f / 1024.f) - mean * mean, 0.f);
  float rs = rsqrtf(var + 1e-5f);
  float4 w4 = ((const float4*)W)[t];
  float4 b4 = ((const float4*)Bv)[t];
  u16x4 o;
  o[0] = f2bf((v.x - mean) * rs * w4.x + b4.x);
  o[1] = f2bf((v.y - mean) * rs * w4.y + b4.y);
  o[2] = f2bf((v.z - mean) * rs * w4.z + b4.z);
  o[3] = f2bf((v.w - mean) * rs * w4.w + b4.w);
  *(u16x4*)(H + (size_t)row * 1024 + t * 4) = o;
}

// ---------------- GEMM: C[M][N] = A[M][K] * B_T[N][K]^T, bf16 in, MFMA ------------------
// MODE 0: qkv epilogue (scatter Q,K,V to [B,H,T,64] coalesced)
// MODE 1: fp32 out = acc + RES
// MODE 2: bf16 out = gelu(acc)
// DBUF: double-buffered LDS with issue-early staging (for 1-block/CU grids)
template <int MODE, bool DBUF>
__global__ __launch_bounds__(256) void gemm_kernel(
    const unsigned short* __restrict__ A, const unsigned short* __restrict__ B,
    const float* __restrict__ RES, void* __restrict__ OUT,
    unsigned short* __restrict__ Qo, unsigned short* __restrict__ Ko,
    unsigned short* __restrict__ Vo, int M, int N, int K) {
  __shared__ __align__(16) unsigned short As[DBUF ? 2 : 1][128 * 64];
  __shared__ __align__(16) unsigned short Bs[DBUF ? 2 : 1][128 * 64];
  const int tid = threadIdx.x;
  const int lane = tid & 63;
  const int wid = __builtin_amdgcn_readfirstlane(tid >> 6);
  const int lane16 = lane & 15, lgrp = lane >> 4;
  const int l8 = lane >> 3;
  const int lb = (lane & 7) * 16;
  const int m0 = blockIdx.y * 128, n0 = blockIdx.x * 128;
  const int wr = wid >> 1, wc = wid & 1;

  f32x4 acc[4][4] = {};

  const char* Ab = (const char*)A + (size_t)m0 * K * 2;
  const char* Bb = (const char*)B + (size_t)n0 * K * 2;
  const size_t rs = (size_t)K * 2;

  auto stage = [&](int k0, int b) {
#pragma unroll
    for (int i = 0; i < 4; ++i) {
      int c = wid * 4 + i;
      gload16(Ab + (size_t)(c * 8 + l8) * rs + (size_t)k0 * 2 + lb,
              (char*)&As[0][0] + b * 16384 + c * 1024);
      gload16(Bb + (size_t)(c * 8 + l8) * rs + (size_t)k0 * 2 + lb,
              (char*)&Bs[0][0] + b * 16384 + c * 1024);
    }
  };

  const int kIt = K / 64;
  if (DBUF) stage(0, 0);

  for (int it = 0; it < kIt; ++it) {
    int cur;
    if (DBUF) {
      cur = it & 1;
      asm volatile("s_waitcnt vmcnt(0)" ::: "memory");
      __syncthreads();
      if (it + 1 < kIt) stage((it + 1) * 64, cur ^ 1);
    } else {
      cur = 0;
      stage(it * 64, 0);
      asm volatile("s_waitcnt vmcnt(0)" ::: "memory");
      __syncthreads();
    }
#pragma unroll
    for (int ks = 0; ks < 2; ++ks) {
      bf16x8 af[4], bfr[4];
#pragma unroll
      for (int mf = 0; mf < 4; ++mf)
        af[mf] = ldb8(&As[cur][(wr * 64 + mf * 16 + lane16) * 64 + ks * 32 + lgrp * 8]);
#pragma unroll
      for (int nf = 0; nf < 4; ++nf)
        bfr[nf] = ldb8(&Bs[cur][(wc * 64 + nf * 16 + lane16) * 64 + ks * 32 + lgrp * 8]);
#pragma unroll
      for (int mf = 0; mf < 4; ++mf)
#pragma unroll
        for (int nf = 0; nf < 4; ++nf)
          acc[mf][nf] = mfma16(af[mf], bfr[nf], acc[mf][nf]);
    }
    if (!DBUF) __syncthreads();
  }

#pragma unroll
  for (int mf = 0; mf < 4; ++mf) {
    int row = m0 + wr * 64 + mf * 16 + lgrp * 4;
#pragma unroll
    for (int nf = 0; nf < 4; ++nf) {
      int col = n0 + wc * 64 + nf * 16 + lane16;
      if (MODE == 1) {
        float* o = (float*)OUT;
#pragma unroll
        for (int i = 0; i < 4; ++i) {
          size_t idx = (size_t)(row + i) * N + col;
          o[idx] = acc[mf][nf][i] + RES[idx];
        }
      } else if (MODE == 2) {
        unsigned short* o = (unsigned short*)OUT;
#pragma unroll
        for (int i = 0; i < 4; ++i)
          o[(size_t)(row + i) * N + col] = f2bf(gelu_t(acc[mf][nf][i]));
      } else {
        int bI = row >> 11, tI = row & 2047;
        unsigned short* dst;
        int dd;
        if (col < 1024) {
          dst = Qo + (size_t)(bI * 16 + (col >> 6)) * 2048 * 64;
          dd = col & 63;
        } else if (col < 2048) {
          int cc = col - 1024;
          dst = Ko + (size_t)(bI * 16 + (cc >> 6)) * 2048 * 64;
          dd = cc & 63;
        } else {
          int cc = col - 2048;
          dst = Vo + (size_t)(bI * 16 + (cc >> 6)) * 2048 * 64;
          dd = cc & 63;
        }
#pragma unroll
        for (int i = 0; i < 4; ++i)
          dst[(size_t)(tI + i) * 64 + dd] = f2bf(acc[mf][nf][i]);
      }
    }
  }
}

// ---------------- causal flash attention -------------------------------------------------
// Q,K: [B*H][T][64] bf16; VT: [B*H][64][T] bf16; O: [B*T][1024] bf16
// QBLK=64 (4 waves x 16 rows), KVBLK=64, double-buffered K/V, 40KB LDS
// -> 4 blocks/CU resident. 1D grid 1024 with XCD-chunked swizzle (4 bh per XCD)
// and heavy/light pairing for per-CU causal-work balance.
__global__ __launch_bounds__(256) void attn_kernel(const unsigned short* __restrict__ Q,
                                                   const unsigned short* __restrict__ Kb,
                                                   const unsigned short* __restrict__ VT,
                                                   unsigned short* __restrict__ O) {
  __shared__ __align__(16) unsigned short Ks[2][64 * 64];
  __shared__ __align__(16) unsigned short Vs[2][64 * 64];
  __shared__ __align__(16) unsigned short Ps[4][16 * 64];
  const int T = 2048;
  // block decode: 4 consecutive bh per XCD; heavy/light pairing within bh
  const int lin = blockIdx.x;
  const int xcd = lin & 7, idx = lin >> 3;
  const int bh = (xcd << 2) + (idx >> 5);
  const int j = idx & 31;
  const int qt = (j & 1) ? (31 - (j >> 1)) : (j >> 1);
  const int q0 = (31 - qt) * 64;  // even j -> large q0 (heavy)

  const int tid = threadIdx.x, lane = tid & 63;
  const int wid = __builtin_amdgcn_readfirstlane(tid >> 6);
  const int lane16 = lane & 15, lgrp = lane >> 4;
  const int l8 = lane >> 3;
  const int swz = ((lane & 7) ^ (l8 & 7)) << 4;  // pre-swizzled global source chunk
  const float SCL2 = 0.18033688011112042f;       // 0.125 * log2(e)

  const int qbase = q0 + wid * 16;
  const unsigned short* qp = Q + ((size_t)bh * T + qbase + lane16) * 64;
  bf16x8 qf[2];
  qf[0] = ldb8(qp + lgrp * 8);
  qf[1] = ldb8(qp + 32 + lgrp * 8);

  const char* kg = (const char*)(Kb + (size_t)bh * T * 64);
  const char* vg = (const char*)(VT + (size_t)bh * 64 * T);
  char* PsB = (char*)&Ps[wid][0];

  auto stage = [&](int kv0, int b) {
#pragma unroll
    for (int i = 0; i < 2; ++i) {
      int c = wid * 2 + i;
      gload16(kg + (size_t)(kv0 + c * 8 + l8) * 128 + swz,
              (char*)&Ks[0][0] + b * 8192 + c * 1024);
      gload16(vg + (size_t)(c * 8 + l8) * (T * 2) + (size_t)kv0 * 2 + swz,
              (char*)&Vs[0][0] + b * 8192 + c * 1024);
    }
  };

  f32x4 acc_o[4] = {};
  float m_run = -1e30f, l_run = 0.f;

  const int nkv = q0 / 64 + 1;
  stage(0, 0);
  for (int kt = 0; kt < nkv; ++kt) {
    const int kv0 = kt * 64;
    const int cur = kt & 1;
    asm volatile("s_waitcnt vmcnt(0)" ::: "memory");
    __syncthreads();
    if (kt + 1 < nkv) stage((kt + 1) * 64, cur ^ 1);

    const char* KsB = (const char*)&Ks[0][0] + cur * 8192;
    const char* VsB = (const char*)&Vs[0][0] + cur * 8192;

    bf16x8 kf[4][2], vf[4][2];
#pragma unroll
    for (int f = 0; f < 4; ++f)
#pragma unroll
      for (int c = 0; c < 2; ++c) {
        int row = f * 16 + lane16;
        int off = (c * 64 + lgrp * 16) ^ ((row & 7) << 4);
        kf[f][c] = ldb8((const unsigned short*)(KsB + row * 128 + off));
        vf[f][c] = ldb8((const unsigned short*)(VsB + row * 128 + off));
      }

    const int qrow = qbase + lane16;
    f32x4 accs[4] = {};
    __builtin_amdgcn_s_setprio(1);
#pragma unroll
    for (int kvf = 0; kvf < 4; ++kvf)
#pragma unroll
      for (int c = 0; c < 2; ++c)
        accs[kvf] = mfma16(kf[kvf][c], qf[c], accs[kvf]);
    __builtin_amdgcn_s_setprio(0);

    float sc[16];
    if (kv0 + 64 <= qbase) {
      // fully-unmasked tile for this wave (wave-uniform branch)
#pragma unroll
      for (int kvf = 0; kvf < 4; ++kvf)
#pragma unroll
        for (int i = 0; i < 4; ++i)
          sc[kvf * 4 + i] = accs[kvf][i] * SCL2;
    } else {
#pragma unroll
      for (int kvf = 0; kvf < 4; ++kvf)
#pragma unroll
        for (int i = 0; i < 4; ++i) {
          int kv = kv0 + kvf * 16 + lgrp * 4 + i;
          float v = accs[kvf][i] * SCL2;
          sc[kvf * 4 + i] = (kv > qrow) ? -1e30f : v;
        }
    }
    float tmax = sc[0];
#pragma unroll
    for (int jj = 1; jj < 16; ++jj) tmax = fmaxf(tmax, sc[jj]);
    tmax = fmaxf(tmax, __shfl_xor(tmax, 16));
    tmax = fmaxf(tmax, __shfl_xor(tmax, 32));
    float m_c = m_run;
    if (!__all(tmax <= m_c + 8.f)) {  // defer-max (T13)
      float m_new = fmaxf(m_c, tmax);
      float corr = exp2f(m_c - m_new);
      l_run *= corr;
      float cf0 = __shfl(corr, lgrp * 4 + 0);
      float cf1 = __shfl(corr, lgrp * 4 + 1);
      float cf2 = __shfl(corr, lgrp * 4 + 2);
      float cf3 = __shfl(corr, lgrp * 4 + 3);
#pragma unroll
      for (int df = 0; df < 4; ++df) {
        acc_o[df][0] *= cf0; acc_o[df][1] *= cf1;
        acc_o[df][2] *= cf2; acc_o[df][3] *= cf3;
      }
      m_run = m_new;
      m_c = m_new;
    }
    float p[16];
    float psum = 0.f;
#pragma unroll
    for (int jj = 0; jj < 16; ++jj) { p[jj] = exp2f(sc[jj] - m_c); psum += p[jj]; }
    psum += __shfl_xor(psum, 16);
    psum += __shfl_xor(psum, 32);
    l_run += psum;

    const int prow = lane16;
#pragma unroll
    for (int kvf = 0; kvf < 4; ++kvf) {
      u16x4 pk;
#pragma unroll
      for (int i = 0; i < 4; ++i) pk[i] = f2bf(p[kvf * 4 + i]);
      *(u16x4*)(PsB + prow * 128 + ((kvf * 32 + lgrp * 8) ^ ((prow & 7) << 4))) = pk;
    }
    bf16x8 pf[2];
#pragma unroll
    for (int c = 0; c < 2; ++c)
      pf[c] = ldb8((const unsigned short*)(PsB + prow * 128 +
                   ((c * 64 + lgrp * 16) ^ ((prow & 7) << 4))));
    __builtin_amdgcn_s_setprio(1);
#pragma unroll
    for (int c = 0; c < 2; ++c)
#pragma unroll
      for (int df = 0; df < 4; ++df)
        acc_o[df] = mfma16(pf[c], vf[df][c], acc_o[df]);
    __builtin_amdgcn_s_setprio(0);
  }

  const int b = bh >> 4, hh = bh & 15;
  float il = 1.f / l_run;
  float f0 = __shfl(il, lgrp * 4 + 0);
  float f1 = __shfl(il, lgrp * 4 + 1);
  float f2 = __shfl(il, lgrp * 4 + 2);
  float f3 = __shfl(il, lgrp * 4 + 3);
#pragma unroll
  for (int df = 0; df < 4; ++df) {
    int col = hh * 64 + df * 16 + lane16;
    size_t base = ((size_t)(b * T + qbase + lgrp * 4)) * 1024 + col;
    O[base] = f2bf(acc_o[df][0] * f0);
    O[base + 1024] = f2bf(acc_o[df][1] * f1);
    O[base + 2048] = f2bf(acc_o[df][2] * f2);
    O[base + 3072] = f2bf(acc_o[df][3] * f3);
  }
}

// ---------------- launcher ---------------------------------------------------------------
extern "C" void kernel_launch(void* const* d_in, const int* in_sizes, int n_in,
                              void* d_out, int out_size, void* d_ws, size_t ws_size,
                              hipStream_t stream) {
  (void)in_sizes; (void)n_in; (void)out_size; (void)ws_size;
  const float* x    = (const float*)d_in[0];
  const float* ln1w = (const float*)d_in[1];
  const float* ln1b = (const float*)d_in[2];
  const float* ln2w = (const float*)d_in[3];
  const float* ln2b = (const float*)d_in[4];
  const float* wqkv = (const float*)d_in[5];
  const float* wprj = (const float*)d_in[6];
  const float* wff1 = (const float*)d_in[7];
  const float* wff2 = (const float*)d_in[8];
  float* out = (float*)d_out;
  char* ws = (char*)d_ws;

  unsigned short* h      = (unsigned short*)(ws + 0);
  unsigned short* wqkvT  = (unsigned short*)(ws + 8388608);
  unsigned short* wprjT  = (unsigned short*)(ws + 14680064);
  unsigned short* wff1T  = (unsigned short*)(ws + 16777216);
  unsigned short* wff2T  = (unsigned short*)(ws + 25165824);
  unsigned short* qb     = (unsigned short*)(ws + 33554432);
  unsigned short* kb     = (unsigned short*)(ws + 41943040);
  unsigned short* vT     = (unsigned short*)(ws + 50331648);
  unsigned short* ob     = (unsigned short*)(ws + 58720256);
  unsigned short* h2     = (unsigned short*)(ws + 67108864);  // also Vo (dead before LN2)
  unsigned short* a1     = (unsigned short*)(ws + 75497472);
  unsigned short* vo     = h2;

  // weight convert+transpose: out[C][R] = in[R][C]^T
  tconv_kernel<<<dim3(48, 16), 256, 0, stream>>>(wqkv, wqkvT, 1024, 3072);
  tconv_kernel<<<dim3(16, 16), 256, 0, stream>>>(wprj, wprjT, 1024, 1024);
  tconv_kernel<<<dim3(64, 16), 256, 0, stream>>>(wff1, wff1T, 1024, 4096);
  tconv_kernel<<<dim3(16, 64), 256, 0, stream>>>(wff2, wff2T, 4096, 1024);

  // LN1
  ln_kernel<<<4096, 256, 0, stream>>>(x, ln1w, ln1b, h);
  // QKV projection (coalesced Q,K,V stores) — 768 blocks, keep single-buffer
  gemm_kernel<0, false><<<dim3(24, 32), 256, 0, stream>>>(h, wqkvT, nullptr, nullptr,
                                                          qb, kb, vo, 4096, 3072, 1024);
  // V transpose to [B,H,64,T]
  vtrans_kernel<<<dim3(32, 32), 256, 0, stream>>>(vo, vT);
  // attention — QBLK=64, 1024 blocks, 4/CU resident
  attn_kernel<<<1024, 256, 0, stream>>>(qb, kb, vT, ob);
  // out-proj + residual (fp32) — 256 blocks (1/CU): double-buffered
  gemm_kernel<1, true><<<dim3(8, 32), 256, 0, stream>>>(ob, wprjT, x, out,
                                                        nullptr, nullptr, nullptr, 4096, 1024, 1024);
  // LN2
  ln_kernel<<<4096, 256, 0, stream>>>(out, ln2w, ln2b, h2);
  // FF1 + GELU — 1024 blocks, keep single-buffer
  gemm_kernel<2, false><<<dim3(32, 32), 256, 0, stream>>>(h2, wff1T, nullptr, a1,
                                                          nullptr, nullptr, nullptr, 4096, 4096, 1024);
  // FF2 + residual (fp32) — 256 blocks (1/CU): double-buffered
  gemm_kernel<1, true><<<dim3(8, 32), 256, 0, stream>>>(a1, wff2T, out, out,
                                                        nullptr, nullptr, nullptr, 4096, 1024, 4096);
}

// Round 8
// 387.932 us; speedup vs baseline: 1.2584x; 1.0763x over previous
//
#include <hip/hip_runtime.h>

typedef __attribute__((ext_vector_type(8))) __bf16 bf16x8;
typedef __attribute__((ext_vector_type(8))) unsigned short u16x8;
typedef __attribute__((ext_vector_type(4))) unsigned short u16x4;
typedef __attribute__((ext_vector_type(4))) float f32x4;

__device__ __forceinline__ unsigned short f2bf(float f) {
  return __builtin_bit_cast(unsigned short, (__bf16)f);
}

__device__ __forceinline__ bf16x8 ldb8(const unsigned short* p) {
  u16x8 u = *(const u16x8*)p;
  return __builtin_bit_cast(bf16x8, u);
}

__device__ __forceinline__ f32x4 mfma16(bf16x8 a, bf16x8 b, f32x4 c) {
  return __builtin_amdgcn_mfma_f32_16x16x32_bf16(a, b, c, 0, 0, 0);
}

__device__ __forceinline__ void gload16(const void* g, void* l) {
  __builtin_amdgcn_global_load_lds(
      (const __attribute__((address_space(1))) void*)g,
      (__attribute__((address_space(3))) void*)l, 16, 0, 0);
}

__device__ __forceinline__ float gelu_t(float x) {
  float u = x * (0.7978845608028654f * (1.0f + 0.044715f * x * x));
  return 0.5f * x * (1.0f + u / (1.0f + fabsf(u)));
}

// ---------------- transpose + fp32->bf16 convert: out[C][R] = bf16(in[R][C]) --------------
__global__ __launch_bounds__(256) void tconv_kernel(const float* __restrict__ in,
                                                    unsigned short* __restrict__ out,
                                                    int R, int C) {
  __shared__ unsigned short tile[64][68];
  int r0 = blockIdx.y * 64, c0 = blockIdx.x * 64;
  int tx = threadIdx.x & 63, tg = threadIdx.x >> 6;
  for (int rr = tg; rr < 64; rr += 4)
    tile[tx][rr] = f2bf(in[(size_t)(r0 + rr) * C + c0 + tx]);
  __syncthreads();
  for (int cc = tg; cc < 64; cc += 4)
    out[(size_t)(c0 + cc) * R + r0 + tx] = tile[cc][tx];
}

// ---------------- batched V transpose: VT[bh][d][t] = V[bh][t][d] ------------------------
__global__ __launch_bounds__(256) void vtrans_kernel(const unsigned short* __restrict__ V,
                                                     unsigned short* __restrict__ VT) {
  __shared__ unsigned short tile[64][68];
  int bh = blockIdx.y;
  int t0 = blockIdx.x * 64;
  const unsigned short* in = V + (size_t)bh * 2048 * 64;
  unsigned short* out = VT + (size_t)bh * 64 * 2048;
  int tx = threadIdx.x & 63, tg = threadIdx.x >> 6;
  for (int rr = tg; rr < 64; rr += 4)
    tile[tx][rr] = in[(size_t)(t0 + rr) * 64 + tx];
  __syncthreads();
  for (int dd = tg; dd < 64; dd += 4)
    out[(size_t)dd * 2048 + t0 + tx] = tile[dd][tx];
}

// ---------------- LayerNorm: one block per row of 1024, bf16 out -------------------------
__global__ __launch_bounds__(256) void ln_kernel(const float* __restrict__ X,
                                                 const float* __restrict__ W,
                                                 const float* __restrict__ Bv,
                                                 unsigned short* __restrict__ H) {
  int row = blockIdx.x;
  int t = threadIdx.x;
  float4 v = ((const float4*)(X + (size_t)row * 1024))[t];
  float s = v.x + v.y + v.z + v.w;
  float s2 = v.x * v.x + v.y * v.y + v.z * v.z + v.w * v.w;
#pragma unroll
  for (int m = 32; m >= 1; m >>= 1) { s += __shfl_xor(s, m); s2 += __shfl_xor(s2, m); }
  __shared__ float red[8];
  if ((t & 63) == 0) { red[t >> 6] = s; red[4 + (t >> 6)] = s2; }
  __syncthreads();
  s = red[0] + red[1] + red[2] + red[3];
  s2 = red[4] + red[5] + red[6] + red[7];
  float mean = s * (1.f / 1024.f);
  float var = fmaxf(s2 * (1.f / 1024.f) - mean * mean, 0.f);
  float rs = rsqrtf(var + 1e-5f);
  float4 w4 = ((const float4*)W)[t];
  float4 b4 = ((const float4*)Bv)[t];
  u16x4 o;
  o[0] = f2bf((v.x - mean) * rs * w4.x + b4.x);
  o[1] = f2bf((v.y - mean) * rs * w4.y + b4.y);
  o[2] = f2bf((v.z - mean) * rs * w4.z + b4.z);
  o[3] = f2bf((v.w - mean) * rs * w4.w + b4.w);
  *(u16x4*)(H + (size_t)row * 1024 + t * 4) = o;
}

// ---------------- GEMM: C[M][N] = A[M][K] * B_T[N][K]^T, bf16 in, MFMA ------------------
// MODE 0: qkv epilogue (scatter Q,K,V to [B,H,T,64] coalesced)
// MODE 1: fp32 out = acc + RES
// MODE 2: bf16 out = gelu(acc)
// DBUF: double-buffered LDS with issue-early staging (for 1-block/CU grids)
template <int MODE, bool DBUF>
__global__ __launch_bounds__(256) void gemm_kernel(
    const unsigned short* __restrict__ A, const unsigned short* __restrict__ B,
    const float* __restrict__ RES, void* __restrict__ OUT,
    unsigned short* __restrict__ Qo, unsigned short* __restrict__ Ko,
    unsigned short* __restrict__ Vo, int M, int N, int K) {
  __shared__ __align__(16) unsigned short As[DBUF ? 2 : 1][128 * 64];
  __shared__ __align__(16) unsigned short Bs[DBUF ? 2 : 1][128 * 64];
  const int tid = threadIdx.x;
  const int lane = tid & 63;
  const int wid = __builtin_amdgcn_readfirstlane(tid >> 6);
  const int lane16 = lane & 15, lgrp = lane >> 4;
  const int l8 = lane >> 3;
  const int lb = (lane & 7) * 16;
  const int m0 = blockIdx.y * 128, n0 = blockIdx.x * 128;
  const int wr = wid >> 1, wc = wid & 1;

  f32x4 acc[4][4] = {};

  const char* Ab = (const char*)A + (size_t)m0 * K * 2;
  const char* Bb = (const char*)B + (size_t)n0 * K * 2;
  const size_t rs = (size_t)K * 2;

  auto stage = [&](int k0, int b) {
#pragma unroll
    for (int i = 0; i < 4; ++i) {
      int c = wid * 4 + i;
      gload16(Ab + (size_t)(c * 8 + l8) * rs + (size_t)k0 * 2 + lb,
              (char*)&As[0][0] + b * 16384 + c * 1024);
      gload16(Bb + (size_t)(c * 8 + l8) * rs + (size_t)k0 * 2 + lb,
              (char*)&Bs[0][0] + b * 16384 + c * 1024);
    }
  };

  const int kIt = K / 64;
  if (DBUF) stage(0, 0);

  for (int it = 0; it < kIt; ++it) {
    int cur;
    if (DBUF) {
      cur = it & 1;
      asm volatile("s_waitcnt vmcnt(0)" ::: "memory");
      __syncthreads();
      if (it + 1 < kIt) stage((it + 1) * 64, cur ^ 1);
    } else {
      cur = 0;
      stage(it * 64, 0);
      asm volatile("s_waitcnt vmcnt(0)" ::: "memory");
      __syncthreads();
    }
#pragma unroll
    for (int ks = 0; ks < 2; ++ks) {
      bf16x8 af[4], bfr[4];
#pragma unroll
      for (int mf = 0; mf < 4; ++mf)
        af[mf] = ldb8(&As[cur][(wr * 64 + mf * 16 + lane16) * 64 + ks * 32 + lgrp * 8]);
#pragma unroll
      for (int nf = 0; nf < 4; ++nf)
        bfr[nf] = ldb8(&Bs[cur][(wc * 64 + nf * 16 + lane16) * 64 + ks * 32 + lgrp * 8]);
#pragma unroll
      for (int mf = 0; mf < 4; ++mf)
#pragma unroll
        for (int nf = 0; nf < 4; ++nf)
          acc[mf][nf] = mfma16(af[mf], bfr[nf], acc[mf][nf]);
    }
    if (!DBUF) __syncthreads();
  }

#pragma unroll
  for (int mf = 0; mf < 4; ++mf) {
    int row = m0 + wr * 64 + mf * 16 + lgrp * 4;
#pragma unroll
    for (int nf = 0; nf < 4; ++nf) {
      int col = n0 + wc * 64 + nf * 16 + lane16;
      if (MODE == 1) {
        float* o = (float*)OUT;
#pragma unroll
        for (int i = 0; i < 4; ++i) {
          size_t idx = (size_t)(row + i) * N + col;
          o[idx] = acc[mf][nf][i] + RES[idx];
        }
      } else if (MODE == 2) {
        unsigned short* o = (unsigned short*)OUT;
#pragma unroll
        for (int i = 0; i < 4; ++i)
          o[(size_t)(row + i) * N + col] = f2bf(gelu_t(acc[mf][nf][i]));
      } else {
        int bI = row >> 11, tI = row & 2047;
        unsigned short* dst;
        int dd;
        if (col < 1024) {
          dst = Qo + (size_t)(bI * 16 + (col >> 6)) * 2048 * 64;
          dd = col & 63;
        } else if (col < 2048) {
          int cc = col - 1024;
          dst = Ko + (size_t)(bI * 16 + (cc >> 6)) * 2048 * 64;
          dd = cc & 63;
        } else {
          int cc = col - 2048;
          dst = Vo + (size_t)(bI * 16 + (cc >> 6)) * 2048 * 64;
          dd = cc & 63;
        }
#pragma unroll
        for (int i = 0; i < 4; ++i)
          dst[(size_t)(tI + i) * 64 + dd] = f2bf(acc[mf][nf][i]);
      }
    }
  }
}

// ---------------- causal flash attention -------------------------------------------------
// Q,K: [B*H][T][64] bf16; VT: [B*H][64][T] bf16; O: [B*T][1024] bf16
// QBLK=64 (4 waves x 16 rows), KVBLK=64, double-buffered K/V, 40KB LDS, 4 blocks/CU.
// Block decode matched to XCD/CU round-robin dispatch: a CU's 4 blocks (lin stride 256)
// get q-tiles {heavy,light,heavy,light} summing to exactly 66 iters on every CU.
__global__ __launch_bounds__(256) void attn_kernel(const unsigned short* __restrict__ Q,
                                                   const unsigned short* __restrict__ Kb,
                                                   const unsigned short* __restrict__ VT,
                                                   unsigned short* __restrict__ O) {
  __shared__ __align__(16) unsigned short Ks[2][64 * 64];
  __shared__ __align__(16) unsigned short Vs[2][64 * 64];
  __shared__ __align__(16) unsigned short Ps[4][16 * 64];
  const int T = 2048;
  // lin = c + 256*k, c -> fixed CU (XCD = c&7), k = 0..3 resident rounds
  const int lin = blockIdx.x;
  const int c_ = lin & 255, kk = lin >> 8;
  const int bh = c_ & 31;                       // 4 heads per XCD (c&7 interleave)
  const int s_ = ((c_ >> 5) << 2) + kk;         // 0..31, 4 consecutive slots per CU
  const int qt = (s_ & 1) ? (s_ >> 1) : (31 - (s_ >> 1));  // heavy/light pairing, bijective
  const int q0 = qt * 64;

  const int tid = threadIdx.x, lane = tid & 63;
  const int wid = __builtin_amdgcn_readfirstlane(tid >> 6);
  const int lane16 = lane & 15, lgrp = lane >> 4;
  const int l8 = lane >> 3;
  const int swz = ((lane & 7) ^ (l8 & 7)) << 4;  // pre-swizzled global source chunk
  const float SCL2 = 0.18033688011112042f;       // 0.125 * log2(e)

  const int qbase = q0 + wid * 16;
  const unsigned short* qp = Q + ((size_t)bh * T + qbase + lane16) * 64;
  bf16x8 qf[2];
  qf[0] = ldb8(qp + lgrp * 8);
  qf[1] = ldb8(qp + 32 + lgrp * 8);

  const char* kg = (const char*)(Kb + (size_t)bh * T * 64);
  const char* vg = (const char*)(VT + (size_t)bh * 64 * T);
  char* PsB = (char*)&Ps[wid][0];

  auto stage = [&](int kv0, int b) {
#pragma unroll
    for (int i = 0; i < 2; ++i) {
      int c = wid * 2 + i;
      gload16(kg + (size_t)(kv0 + c * 8 + l8) * 128 + swz,
              (char*)&Ks[0][0] + b * 8192 + c * 1024);
      gload16(vg + (size_t)(c * 8 + l8) * (T * 2) + (size_t)kv0 * 2 + swz,
              (char*)&Vs[0][0] + b * 8192 + c * 1024);
    }
  };

  f32x4 acc_o[4] = {};
  float m_run = -1e30f, l_run = 0.f;

  const int nkv = q0 / 64 + 1;
  stage(0, 0);
  for (int kt = 0; kt < nkv; ++kt) {
    const int kv0 = kt * 64;
    const int cur = kt & 1;
    asm volatile("s_waitcnt vmcnt(0)" ::: "memory");
    __syncthreads();
    if (kt + 1 < nkv) stage((kt + 1) * 64, cur ^ 1);

    const char* KsB = (const char*)&Ks[0][0] + cur * 8192;
    const char* VsB = (const char*)&Vs[0][0] + cur * 8192;

    bf16x8 kf[4][2], vf[4][2];
#pragma unroll
    for (int f = 0; f < 4; ++f)
#pragma unroll
      for (int c = 0; c < 2; ++c) {
        int row = f * 16 + lane16;
        int off = (c * 64 + lgrp * 16) ^ ((row & 7) << 4);
        kf[f][c] = ldb8((const unsigned short*)(KsB + row * 128 + off));
        vf[f][c] = ldb8((const unsigned short*)(VsB + row * 128 + off));
      }

    const int qrow = qbase + lane16;
    f32x4 accs[4] = {};
    __builtin_amdgcn_s_setprio(1);
#pragma unroll
    for (int kvf = 0; kvf < 4; ++kvf)
#pragma unroll
      for (int c = 0; c < 2; ++c)
        accs[kvf] = mfma16(kf[kvf][c], qf[c], accs[kvf]);
    __builtin_amdgcn_s_setprio(0);

    // raw (unscaled) scores; mask with -1e30; scale folded into fmaf at exp2
    float sc[16];
    if (kv0 + 64 <= qbase) {
#pragma unroll
      for (int kvf = 0; kvf < 4; ++kvf)
#pragma unroll
        for (int i = 0; i < 4; ++i)
          sc[kvf * 4 + i] = accs[kvf][i];
    } else {
#pragma unroll
      for (int kvf = 0; kvf < 4; ++kvf)
#pragma unroll
        for (int i = 0; i < 4; ++i) {
          int kv = kv0 + kvf * 16 + lgrp * 4 + i;
          sc[kvf * 4 + i] = (kv > qrow) ? -1e30f : accs[kvf][i];
        }
    }
    float tmax = sc[0];
#pragma unroll
    for (int jj = 1; jj < 16; ++jj) tmax = fmaxf(tmax, sc[jj]);
    tmax = fmaxf(tmax, __shfl_xor(tmax, 16));
    tmax = fmaxf(tmax, __shfl_xor(tmax, 32));
    tmax *= SCL2;  // into log2-domain
    float m_c = m_run;
    if (!__all(tmax <= m_c + 8.f)) {  // defer-max (T13)
      float m_new = fmaxf(m_c, tmax);
      float corr = exp2f(m_c - m_new);
      l_run *= corr;
      float cf0 = __shfl(corr, lgrp * 4 + 0);
      float cf1 = __shfl(corr, lgrp * 4 + 1);
      float cf2 = __shfl(corr, lgrp * 4 + 2);
      float cf3 = __shfl(corr, lgrp * 4 + 3);
#pragma unroll
      for (int df = 0; df < 4; ++df) {
        acc_o[df][0] *= cf0; acc_o[df][1] *= cf1;
        acc_o[df][2] *= cf2; acc_o[df][3] *= cf3;
      }
      m_run = m_new;
      m_c = m_new;
    }
    float p[16];
    float psum = 0.f;
#pragma unroll
    for (int jj = 0; jj < 16; ++jj) {
      p[jj] = exp2f(fmaf(sc[jj], SCL2, -m_c));
      psum += p[jj];
    }
    psum += __shfl_xor(psum, 16);
    psum += __shfl_xor(psum, 32);
    l_run += psum;

    const int prow = lane16;
#pragma unroll
    for (int kvf = 0; kvf < 4; ++kvf) {
      u16x4 pk;
#pragma unroll
      for (int i = 0; i < 4; ++i) pk[i] = f2bf(p[kvf * 4 + i]);
      *(u16x4*)(PsB + prow * 128 + ((kvf * 32 + lgrp * 8) ^ ((prow & 7) << 4))) = pk;
    }
    bf16x8 pf[2];
#pragma unroll
    for (int c = 0; c < 2; ++c)
      pf[c] = ldb8((const unsigned short*)(PsB + prow * 128 +
                   ((c * 64 + lgrp * 16) ^ ((prow & 7) << 4))));
    __builtin_amdgcn_s_setprio(1);
#pragma unroll
    for (int c = 0; c < 2; ++c)
#pragma unroll
      for (int df = 0; df < 4; ++df)
        acc_o[df] = mfma16(pf[c], vf[df][c], acc_o[df]);
    __builtin_amdgcn_s_setprio(0);
  }

  const int b = bh >> 4, hh = bh & 15;
  float il = 1.f / l_run;
  float f0 = __shfl(il, lgrp * 4 + 0);
  float f1 = __shfl(il, lgrp * 4 + 1);
  float f2 = __shfl(il, lgrp * 4 + 2);
  float f3 = __shfl(il, lgrp * 4 + 3);
#pragma unroll
  for (int df = 0; df < 4; ++df) {
    int col = hh * 64 + df * 16 + lane16;
    size_t base = ((size_t)(b * T + qbase + lgrp * 4)) * 1024 + col;
    O[base] = f2bf(acc_o[df][0] * f0);
    O[base + 1024] = f2bf(acc_o[df][1] * f1);
    O[base + 2048] = f2bf(acc_o[df][2] * f2);
    O[base + 3072] = f2bf(acc_o[df][3] * f3);
  }
}

// ---------------- launcher ---------------------------------------------------------------
extern "C" void kernel_launch(void* const* d_in, const int* in_sizes, int n_in,
                              void* d_out, int out_size, void* d_ws, size_t ws_size,
                              hipStream_t stream) {
  (void)in_sizes; (void)n_in; (void)out_size; (void)ws_size;
  const float* x    = (const float*)d_in[0];
  const float* ln1w = (const float*)d_in[1];
  const float* ln1b = (const float*)d_in[2];
  const float* ln2w = (const float*)d_in[3];
  const float* ln2b = (const float*)d_in[4];
  const float* wqkv = (const float*)d_in[5];
  const float* wprj = (const float*)d_in[6];
  const float* wff1 = (const float*)d_in[7];
  const float* wff2 = (const float*)d_in[8];
  float* out = (float*)d_out;
  char* ws = (char*)d_ws;

  unsigned short* h      = (unsigned short*)(ws + 0);
  unsigned short* wqkvT  = (unsigned short*)(ws + 8388608);
  unsigned short* wprjT  = (unsigned short*)(ws + 14680064);
  unsigned short* wff1T  = (unsigned short*)(ws + 16777216);
  unsigned short* wff2T  = (unsigned short*)(ws + 25165824);
  unsigned short* qb     = (unsigned short*)(ws + 33554432);
  unsigned short* kb     = (unsigned short*)(ws + 41943040);
  unsigned short* vT     = (unsigned short*)(ws + 50331648);
  unsigned short* ob     = (unsigned short*)(ws + 58720256);
  unsigned short* h2     = (unsigned short*)(ws + 67108864);  // also Vo (dead before LN2)
  unsigned short* a1     = (unsigned short*)(ws + 75497472);
  unsigned short* vo     = h2;

  // weight convert+transpose: out[C][R] = in[R][C]^T
  tconv_kernel<<<dim3(48, 16), 256, 0, stream>>>(wqkv, wqkvT, 1024, 3072);
  tconv_kernel<<<dim3(16, 16), 256, 0, stream>>>(wprj, wprjT, 1024, 1024);
  tconv_kernel<<<dim3(64, 16), 256, 0, stream>>>(wff1, wff1T, 1024, 4096);
  tconv_kernel<<<dim3(16, 64), 256, 0, stream>>>(wff2, wff2T, 4096, 1024);

  // LN1
  ln_kernel<<<4096, 256, 0, stream>>>(x, ln1w, ln1b, h);
  // QKV projection (coalesced Q,K,V stores) — 768 blocks, keep single-buffer
  gemm_kernel<0, false><<<dim3(24, 32), 256, 0, stream>>>(h, wqkvT, nullptr, nullptr,
                                                          qb, kb, vo, 4096, 3072, 1024);
  // V transpose to [B,H,64,T]
  vtrans_kernel<<<dim3(32, 32), 256, 0, stream>>>(vo, vT);
  // attention — QBLK=64, 1024 blocks, 4/CU resident, per-CU balanced decode
  attn_kernel<<<1024, 256, 0, stream>>>(qb, kb, vT, ob);
  // out-proj + residual (fp32) — 256 blocks (1/CU): double-buffered
  gemm_kernel<1, true><<<dim3(8, 32), 256, 0, stream>>>(ob, wprjT, x, out,
                                                        nullptr, nullptr, nullptr, 4096, 1024, 1024);
  // LN2
  ln_kernel<<<4096, 256, 0, stream>>>(out, ln2w, ln2b, h2);
  // FF1 + GELU — 1024 blocks, keep single-buffer
  gemm_kernel<2, false><<<dim3(32, 32), 256, 0, stream>>>(h2, wff1T, nullptr, a1,
                                                          nullptr, nullptr, nullptr, 4096, 4096, 1024);
  // FF2 + residual (fp32) — 256 blocks (1/CU): double-buffered
  gemm_kernel<1, true><<<dim3(8, 32), 256, 0, stream>>>(a1, wff2T, out, out,
                                                        nullptr, nullptr, nullptr, 4096, 1024, 4096);
}